// Round 1
// baseline (3252.756 us; speedup 1.0000x reference)
//
#include <hip/hip_runtime.h>
#include <math.h>

#define D_    256
#define NH    8
#define DHD   32
#define NLV   4
#define NPT   4
#define NVT   8
#define NSEEN 64
#define TVT   72
#define FF    1024
#define BB    2
#define LSP   21760
#define LQ    21792
#define NBQ   (BB*LQ)      // 43584
#define ROWS  16

// ---------------- helpers ----------------

__device__ __forceinline__ float fetch_in(const float* __restrict__ src, const float* __restrict__ pos,
                                          const float* __restrict__ sel, int b, int i, int c, bool addpos)
{
    if (i < LSP) {
        size_t g = ((size_t)b * LSP + i) * D_ + c;
        float v = src[g];
        if (addpos) v += pos[g];
        return v;
    }
    return sel[((size_t)b * (NLV * NVT) + (i - LSP)) * D_ + c];
}

// block of 256 threads (4 waves): sum-reduce a and b across the block
__device__ __forceinline__ void blockReduce2_256(float& a, float& b, float* red, int tid)
{
#pragma unroll
    for (int off = 32; off > 0; off >>= 1) {
        a += __shfl_down(a, off, 64);
        b += __shfl_down(b, off, 64);
    }
    __syncthreads();                    // protect red[] from previous use
    int wid = tid >> 6;
    if ((tid & 63) == 0) { red[wid] = a; red[wid + 4] = b; }
    __syncthreads();
    a = red[0] + red[1] + red[2] + red[3];
    b = red[4] + red[5] + red[6] + red[7];
}

// ---------------- big GEMMs (M = 43584) ----------------
// one block = 16 rows x 256 cols; thread j owns column j for all 16 rows.

template<int MODE>  // 0: A = concat(src, sel)   1: A = concat(src+pos, sel)
__global__ __launch_bounds__(256) void gemm256_k(const float* __restrict__ src, const float* __restrict__ pos,
                                                 const float* __restrict__ sel, const float* __restrict__ W,
                                                 const float* __restrict__ bias, float* __restrict__ out)
{
    __shared__ float As[ROWS][D_];
    const int tid = threadIdx.x;
    const int row0 = blockIdx.x * ROWS;
    for (int idx = tid; idx < ROWS * D_; idx += 256) {
        int r = idx >> 8, c = idx & 255;
        int row = row0 + r;
        int b = row / LQ, i = row - b * LQ;
        As[r][c] = fetch_in(src, pos, sel, b, i, c, MODE == 1);
    }
    __syncthreads();
    float acc[ROWS];
#pragma unroll
    for (int r = 0; r < ROWS; r++) acc[r] = 0.f;
    const int j = tid;
    for (int i = 0; i < D_; i += 4) {
        float w0 = W[(size_t)(i + 0) * D_ + j];
        float w1 = W[(size_t)(i + 1) * D_ + j];
        float w2 = W[(size_t)(i + 2) * D_ + j];
        float w3 = W[(size_t)(i + 3) * D_ + j];
#pragma unroll
        for (int r = 0; r < ROWS; r++) {
            float4 a = *(const float4*)(&As[r][i]);
            acc[r] = fmaf(a.x, w0, acc[r]);
            acc[r] = fmaf(a.y, w1, acc[r]);
            acc[r] = fmaf(a.z, w2, acc[r]);
            acc[r] = fmaf(a.w, w3, acc[r]);
        }
    }
    float bj = bias[j];
#pragma unroll
    for (int r = 0; r < ROWS; r++)
        out[(size_t)(row0 + r) * D_ + j] = acc[r] + bj;
}

// logits GEMM (N=384) with fused per-48-group softmax -> wall (NBQ, 384)
__global__ __launch_bounds__(384) void gemm_logits_k(const float* __restrict__ src, const float* __restrict__ pos,
                                                     const float* __restrict__ sel, const float* __restrict__ W,
                                                     const float* __restrict__ bias, float* __restrict__ wall)
{
    __shared__ float As[ROWS][D_];   // 16KB
    __shared__ float Ls[ROWS][384];  // 24KB
    __shared__ float Es[ROWS][384];  // 24KB
    const int tid = threadIdx.x;
    const int row0 = blockIdx.x * ROWS;
    for (int idx = tid; idx < ROWS * D_; idx += 384) {
        int r = idx >> 8, c = idx & 255;
        int row = row0 + r;
        int b = row / LQ, i = row - b * LQ;
        As[r][c] = fetch_in(src, pos, sel, b, i, c, true);
    }
    __syncthreads();
    float acc[ROWS];
#pragma unroll
    for (int r = 0; r < ROWS; r++) acc[r] = 0.f;
    const int j = tid;
    for (int i = 0; i < D_; i += 4) {
        float w0 = W[(size_t)(i + 0) * 384 + j];
        float w1 = W[(size_t)(i + 1) * 384 + j];
        float w2 = W[(size_t)(i + 2) * 384 + j];
        float w3 = W[(size_t)(i + 3) * 384 + j];
#pragma unroll
        for (int r = 0; r < ROWS; r++) {
            float4 a = *(const float4*)(&As[r][i]);
            acc[r] = fmaf(a.x, w0, acc[r]);
            acc[r] = fmaf(a.y, w1, acc[r]);
            acc[r] = fmaf(a.z, w2, acc[r]);
            acc[r] = fmaf(a.w, w3, acc[r]);
        }
    }
    float bj = bias[j];
#pragma unroll
    for (int r = 0; r < ROWS; r++) Ls[r][j] = acc[r] + bj;
    __syncthreads();
    const int g0 = (j / 48) * 48;
    float ev[ROWS];
#pragma unroll
    for (int r = 0; r < ROWS; r++) {
        float m = -1e30f;
        for (int k = 0; k < 48; k++) m = fmaxf(m, Ls[r][g0 + k]);
        ev[r] = __expf(Ls[r][j] - m);
        Es[r][j] = ev[r];
    }
    __syncthreads();
#pragma unroll
    for (int r = 0; r < ROWS; r++) {
        float s = 0.f;
        for (int k = 0; k < 48; k++) s += Es[r][g0 + k];
        wall[(size_t)(row0 + r) * 384 + j] = ev[r] / s;
    }
}

// ---------------- deformable sampling + vt-token attention mix ----------------
// one block per (b, q); 256 threads = 8 heads x 32 dims
__global__ __launch_bounds__(256) void sample_k(const float* __restrict__ value, const float* __restrict__ offb,
                                                const float* __restrict__ wall, const float* __restrict__ refp,
                                                float* __restrict__ attn)
{
    __shared__ float OF[256];
    __shared__ float WA[384];
    __shared__ float RP[8];
    const int bq = blockIdx.x;
    const int b = bq / LQ;
    const int tid = threadIdx.x;
    OF[tid] = offb[(size_t)bq * 256 + tid];
    for (int idx = tid; idx < 384; idx += 256) WA[idx] = wall[(size_t)bq * 384 + idx];
    if (tid < 8) RP[tid] = refp[(size_t)bq * 8 + tid];
    __syncthreads();
    const int h = tid >> 5, d = tid & 31;
    const size_t vbase = ((size_t)b * LQ) * 256 + (size_t)(h * 32 + d);
    float acc = 0.f;
    const int HL[4] = {128, 64, 32, 16};
    const int S0[4] = {0, 16384, 20480, 21504};
#pragma unroll
    for (int l = 0; l < NLV; l++) {
        const int Wl = HL[l], Hl = HL[l];
        const int s0 = S0[l];
        float rx = RP[l * 2 + 0] * (float)Wl - 0.5f;
        float ry = RP[l * 2 + 1] * (float)Hl - 0.5f;
#pragma unroll
        for (int p = 0; p < NPT; p++) {
            float x = rx + OF[h * 32 + l * 8 + p * 2 + 0];
            float y = ry + OF[h * 32 + l * 8 + p * 2 + 1];
            float wl = WA[h * 48 + l * 12 + p];
            float x0f = floorf(x), y0f = floorf(y);
            int x0 = (int)x0f, y0 = (int)y0f;
            float fx = x - x0f, fy = y - y0f;
            float w00 = (1.f - fx) * (1.f - fy) * wl;
            float w01 = fx * (1.f - fy) * wl;
            float w10 = (1.f - fx) * fy * wl;
            float w11 = fx * fy * wl;
            bool xok0 = (x0 >= 0) && (x0 < Wl);
            bool xok1 = (x0 + 1 >= 0) && (x0 + 1 < Wl);
            bool yok0 = (y0 >= 0) && (y0 < Hl);
            bool yok1 = (y0 + 1 >= 0) && (y0 + 1 < Hl);
            if (xok0 && yok0) acc += w00 * value[vbase + (size_t)(s0 + y0 * Wl + x0) * 256];
            if (xok1 && yok0) acc += w01 * value[vbase + (size_t)(s0 + y0 * Wl + x0 + 1) * 256];
            if (xok0 && yok1) acc += w10 * value[vbase + (size_t)(s0 + (y0 + 1) * Wl + x0) * 256];
            if (xok1 && yok1) acc += w11 * value[vbase + (size_t)(s0 + (y0 + 1) * Wl + x0 + 1) * 256];
        }
    }
#pragma unroll
    for (int l = 0; l < NLV; l++) {
#pragma unroll
        for (int v = 0; v < NVT; v++) {
            acc += WA[h * 48 + l * 12 + 4 + v] * value[vbase + (size_t)(LSP + l * NVT + v) * 256];
        }
    }
    attn[(size_t)bq * 256 + tid] = acc;
}

// ---------------- out-proj + residual + LN1 -> x ----------------
__global__ __launch_bounds__(256) void gemm_out_ln1_k(const float* __restrict__ attn, const float* __restrict__ W,
                                                      const float* __restrict__ bias, const float* __restrict__ src,
                                                      const float* __restrict__ sel, const float* __restrict__ g1,
                                                      const float* __restrict__ be1, float* xsp, float* xtail)
{
    __shared__ float As[ROWS][D_];
    __shared__ float Ts[ROWS][D_];
    __shared__ float red[8];
    const int tid = threadIdx.x;
    const int row0 = blockIdx.x * ROWS;
    for (int idx = tid; idx < ROWS * D_; idx += 256) {
        int r = idx >> 8, c = idx & 255;
        As[r][c] = attn[(size_t)(row0 + r) * D_ + c];
    }
    __syncthreads();
    float acc[ROWS];
#pragma unroll
    for (int r = 0; r < ROWS; r++) acc[r] = 0.f;
    const int j = tid;
    for (int i = 0; i < D_; i += 4) {
        float w0 = W[(size_t)(i + 0) * D_ + j];
        float w1 = W[(size_t)(i + 1) * D_ + j];
        float w2 = W[(size_t)(i + 2) * D_ + j];
        float w3 = W[(size_t)(i + 3) * D_ + j];
#pragma unroll
        for (int r = 0; r < ROWS; r++) {
            float4 a = *(const float4*)(&As[r][i]);
            acc[r] = fmaf(a.x, w0, acc[r]);
            acc[r] = fmaf(a.y, w1, acc[r]);
            acc[r] = fmaf(a.z, w2, acc[r]);
            acc[r] = fmaf(a.w, w3, acc[r]);
        }
    }
    float bj = bias[j];
#pragma unroll
    for (int r = 0; r < ROWS; r++) {
        int row = row0 + r;
        int b = row / LQ, i = row - b * LQ;
        float resid = (i < LSP) ? src[((size_t)b * LSP + i) * D_ + j]
                                : sel[((size_t)b * 32 + (i - LSP)) * D_ + j];
        Ts[r][j] = acc[r] + bj + resid;
    }
    __syncthreads();
    float gj = g1[j], bej = be1[j];
    for (int r = 0; r < ROWS; r++) {
        float v = Ts[r][j];
        float a = v, sq = v * v;
        blockReduce2_256(a, sq, red, tid);
        float mean = a * (1.f / D_);
        float var = sq * (1.f / D_) - mean * mean;
        float ov = (v - mean) * rsqrtf(var + 1e-5f) * gj + bej;
        int row = row0 + r;
        int b = row / LQ, i = row - b * LQ;
        if (i < LSP) xsp[((size_t)b * LSP + i) * D_ + j] = ov;
        else         xtail[((size_t)b * 32 + (i - LSP)) * D_ + j] = ov;
    }
}

// ---------------- FFN (256->1024 relu 1024->256) + residual + LN2, in place on x ----------------
__global__ __launch_bounds__(256) void ffn_ln2_k(const float* __restrict__ W1, const float* __restrict__ b1,
                                                 const float* __restrict__ W2, const float* __restrict__ b2,
                                                 const float* __restrict__ g2, const float* __restrict__ be2,
                                                 float* xsp, float* xtail)
{
    __shared__ float Xs[ROWS][D_];   // 16KB
    __shared__ float Hs[ROWS][FF];   // 64KB
    __shared__ float red[8];
    const int tid = threadIdx.x;
    const int row0 = blockIdx.x * ROWS;
    for (int idx = tid; idx < ROWS * D_; idx += 256) {
        int r = idx >> 8, c = idx & 255;
        int row = row0 + r;
        int b = row / LQ, i = row - b * LQ;
        Xs[r][c] = (i < LSP) ? xsp[((size_t)b * LSP + i) * D_ + c]
                             : xtail[((size_t)b * 32 + (i - LSP)) * D_ + c];
    }
    __syncthreads();
    // GEMM1: x @ W1 -> relu -> Hs
    for (int cch = 0; cch < 4; cch++) {
        int j1 = cch * 256 + tid;
        float acc[ROWS];
#pragma unroll
        for (int r = 0; r < ROWS; r++) acc[r] = 0.f;
        for (int i = 0; i < D_; i += 4) {
            float w0 = W1[(size_t)(i + 0) * FF + j1];
            float w1 = W1[(size_t)(i + 1) * FF + j1];
            float w2 = W1[(size_t)(i + 2) * FF + j1];
            float w3 = W1[(size_t)(i + 3) * FF + j1];
#pragma unroll
            for (int r = 0; r < ROWS; r++) {
                float4 a = *(const float4*)(&Xs[r][i]);
                acc[r] = fmaf(a.x, w0, acc[r]);
                acc[r] = fmaf(a.y, w1, acc[r]);
                acc[r] = fmaf(a.z, w2, acc[r]);
                acc[r] = fmaf(a.w, w3, acc[r]);
            }
        }
        float bb = b1[j1];
#pragma unroll
        for (int r = 0; r < ROWS; r++) Hs[r][j1] = fmaxf(acc[r] + bb, 0.f);
    }
    __syncthreads();
    // GEMM2: Hs @ W2
    float acc2[ROWS];
#pragma unroll
    for (int r = 0; r < ROWS; r++) acc2[r] = 0.f;
    for (int i = 0; i < FF; i += 4) {
        float w0 = W2[(size_t)(i + 0) * D_ + tid];
        float w1 = W2[(size_t)(i + 1) * D_ + tid];
        float w2 = W2[(size_t)(i + 2) * D_ + tid];
        float w3 = W2[(size_t)(i + 3) * D_ + tid];
#pragma unroll
        for (int r = 0; r < ROWS; r++) {
            float4 hh = *(const float4*)(&Hs[r][i]);
            acc2[r] = fmaf(hh.x, w0, acc2[r]);
            acc2[r] = fmaf(hh.y, w1, acc2[r]);
            acc2[r] = fmaf(hh.z, w2, acc2[r]);
            acc2[r] = fmaf(hh.w, w3, acc2[r]);
        }
    }
    float bj = b2[tid], gj = g2[tid], bej = be2[tid];
    __syncthreads();   // all Hs reads done; reuse first 256 cols as T
#pragma unroll
    for (int r = 0; r < ROWS; r++) Hs[r][tid] = acc2[r] + bj + Xs[r][tid];
    __syncthreads();
    for (int r = 0; r < ROWS; r++) {
        float v = Hs[r][tid];
        float a = v, sq = v * v;
        blockReduce2_256(a, sq, red, tid);
        float mean = a * (1.f / D_);
        float var = sq * (1.f / D_) - mean * mean;
        float ov = (v - mean) * rsqrtf(var + 1e-5f) * gj + bej;
        int row = row0 + r;
        int b = row / LQ, i = row - b * LQ;
        if (i < LSP) xsp[((size_t)b * LSP + i) * D_ + tid] = ov;
        else         xtail[((size_t)b * 32 + (i - LSP)) * D_ + tid] = ov;
    }
}

// ---------------- VT transformer layers (per level, T=72) ----------------

__device__ __forceinline__ float fetch_vts(const float* __restrict__ xtail, const float* __restrict__ seen,
                                           int b, int l, int t, int c)
{
    return (t < NVT) ? xtail[((size_t)b * 32 + l * NVT + t) * D_ + c]
                     : seen[(((size_t)b * NLV + l) * NSEEN + (t - NVT)) * D_ + c];
}

// qkv = vts @ wqkv[l] + bqkv[l]    grid (5, 3, 8)
__global__ __launch_bounds__(256) void vt_qkv_k(const float* __restrict__ xtail, const float* __restrict__ seen,
                                                const float* __restrict__ wqkv, const float* __restrict__ bqkv,
                                                float* __restrict__ qkv)
{
    const int rt = blockIdx.x, cb = blockIdx.y, z = blockIdx.z;
    const int b = z >> 2, l = z & 3;
    __shared__ float As[ROWS][D_];
    const int tid = threadIdx.x;
    for (int idx = tid; idx < ROWS * D_; idx += 256) {
        int r = idx >> 8, c = idx & 255;
        int t = rt * ROWS + r;
        As[r][c] = (t < TVT) ? fetch_vts(xtail, seen, b, l, t, c) : 0.f;
    }
    __syncthreads();
    const float* W = wqkv + (size_t)l * D_ * 768;
    const int j = cb * 256 + tid;
    float acc[ROWS];
#pragma unroll
    for (int r = 0; r < ROWS; r++) acc[r] = 0.f;
    for (int i = 0; i < D_; i += 4) {
        float w0 = W[(size_t)(i + 0) * 768 + j];
        float w1 = W[(size_t)(i + 1) * 768 + j];
        float w2 = W[(size_t)(i + 2) * 768 + j];
        float w3 = W[(size_t)(i + 3) * 768 + j];
#pragma unroll
        for (int r = 0; r < ROWS; r++) {
            float4 a = *(const float4*)(&As[r][i]);
            acc[r] = fmaf(a.x, w0, acc[r]);
            acc[r] = fmaf(a.y, w1, acc[r]);
            acc[r] = fmaf(a.z, w2, acc[r]);
            acc[r] = fmaf(a.w, w3, acc[r]);
        }
    }
    float bj = bqkv[l * 768 + j];
#pragma unroll
    for (int r = 0; r < ROWS; r++) {
        int t = rt * ROWS + r;
        if (t < TVT) qkv[((size_t)z * TVT + t) * 768 + j] = acc[r] + bj;
    }
}

// attention per (b,l,h): 64 blocks, 128 threads; threads 0..71 each own a query row
__global__ __launch_bounds__(128) void vt_attn_k(const float* __restrict__ qkv, float* __restrict__ o)
{
    const int z = blockIdx.x;
    const int h = z & 7, bl = z >> 3;
    __shared__ float Qs[TVT][33];   // padded: conflict-free per-lane row reads
    __shared__ float Ks[TVT][DHD];
    __shared__ float Vs[TVT][DHD];
    __shared__ float Ss[TVT][73];
    const int tid = threadIdx.x;
    for (int idx = tid; idx < TVT * DHD; idx += 128) {
        int t = idx >> 5, d = idx & 31;
        const float* base = qkv + ((size_t)bl * TVT + t) * 768 + h * DHD + d;
        Qs[t][d] = base[0];
        Ks[t][d] = base[256];
        Vs[t][d] = base[512];
    }
    __syncthreads();
    if (tid < TVT) {
        const float scale = 0.17677669529663687f;  // 1/sqrt(32)
        float qr[DHD];
#pragma unroll
        for (int d = 0; d < DHD; d++) qr[d] = Qs[tid][d];
        float m = -1e30f;
        for (int k = 0; k < TVT; k++) {
            float s = 0.f;
#pragma unroll
            for (int d = 0; d < DHD; d++) s = fmaf(qr[d], Ks[k][d], s);
            s *= scale;
            Ss[tid][k] = s;
            m = fmaxf(m, s);
        }
        float sum = 0.f;
        for (int k = 0; k < TVT; k++) {
            float e = __expf(Ss[tid][k] - m);
            Ss[tid][k] = e;
            sum += e;
        }
        float inv = 1.f / sum;
        for (int d = 0; d < DHD; d++) {
            float acc = 0.f;
            for (int k = 0; k < TVT; k++) acc = fmaf(Ss[tid][k], Vs[k][d], acc);
            o[((size_t)bl * TVT + tid) * D_ + h * DHD + d] = acc * inv;
        }
    }
}

// o @ wproj[l] + bproj[l] + vts, LN3 -> vts2     grid (5, 1, 8)
__global__ __launch_bounds__(256) void vt_proj_ln3_k(const float* __restrict__ obuf, const float* __restrict__ wproj,
                                                     const float* __restrict__ bproj, const float* __restrict__ xtail,
                                                     const float* __restrict__ seen, const float* __restrict__ g3,
                                                     const float* __restrict__ b3, float* __restrict__ vts2)
{
    const int rt = blockIdx.x, z = blockIdx.z;
    const int b = z >> 2, l = z & 3;
    __shared__ float As[ROWS][D_];
    __shared__ float Ts[ROWS][D_];
    __shared__ float red[8];
    const int tid = threadIdx.x;
    for (int idx = tid; idx < ROWS * D_; idx += 256) {
        int r = idx >> 8, c = idx & 255;
        int t = rt * ROWS + r;
        As[r][c] = (t < TVT) ? obuf[((size_t)z * TVT + t) * D_ + c] : 0.f;
    }
    __syncthreads();
    const float* W = wproj + (size_t)l * D_ * D_;
    const int j = tid;
    float acc[ROWS];
#pragma unroll
    for (int r = 0; r < ROWS; r++) acc[r] = 0.f;
    for (int i = 0; i < D_; i += 4) {
        float w0 = W[(size_t)(i + 0) * D_ + j];
        float w1 = W[(size_t)(i + 1) * D_ + j];
        float w2 = W[(size_t)(i + 2) * D_ + j];
        float w3 = W[(size_t)(i + 3) * D_ + j];
#pragma unroll
        for (int r = 0; r < ROWS; r++) {
            float4 a = *(const float4*)(&As[r][i]);
            acc[r] = fmaf(a.x, w0, acc[r]);
            acc[r] = fmaf(a.y, w1, acc[r]);
            acc[r] = fmaf(a.z, w2, acc[r]);
            acc[r] = fmaf(a.w, w3, acc[r]);
        }
    }
    float bj = bproj[l * D_ + j];
#pragma unroll
    for (int r = 0; r < ROWS; r++) {
        int t = rt * ROWS + r;
        if (t < TVT) Ts[r][j] = acc[r] + bj + fetch_vts(xtail, seen, b, l, t, j);
    }
    __syncthreads();
    float gj = g3[l * D_ + j], bej = b3[l * D_ + j];
    for (int r = 0; r < ROWS; r++) {
        int t = rt * ROWS + r;
        if (t >= TVT) continue;        // uniform across block
        float v = Ts[r][j];
        float a = v, sq = v * v;
        blockReduce2_256(a, sq, red, tid);
        float mean = a * (1.f / D_);
        float var = sq * (1.f / D_) - mean * mean;
        vts2[((size_t)z * TVT + t) * D_ + j] = (v - mean) * rsqrtf(var + 1e-5f) * gj + bej;
    }
}

// MLP (gelu) + residual + LN4 -> route to outputs     grid (5, 1, 8)
__global__ __launch_bounds__(256) void vt_mlp_ln4_k(const float* __restrict__ vts2, const float* __restrict__ wfc1,
                                                    const float* __restrict__ bfc1, const float* __restrict__ wfc2,
                                                    const float* __restrict__ bfc2, const float* __restrict__ g4,
                                                    const float* __restrict__ b4, float* __restrict__ out_seen,
                                                    float* __restrict__ out_sel)
{
    const int rt = blockIdx.x, z = blockIdx.z;
    const int b = z >> 2, l = z & 3;
    __shared__ float Xs[ROWS][D_];
    __shared__ float Hs[ROWS][FF];
    __shared__ float red[8];
    const int tid = threadIdx.x;
    for (int idx = tid; idx < ROWS * D_; idx += 256) {
        int r = idx >> 8, c = idx & 255;
        int t = rt * ROWS + r;
        Xs[r][c] = (t < TVT) ? vts2[((size_t)z * TVT + t) * D_ + c] : 0.f;
    }
    __syncthreads();
    const float* W1 = wfc1 + (size_t)l * D_ * FF;
    const float* W2 = wfc2 + (size_t)l * FF * D_;
    for (int cch = 0; cch < 4; cch++) {
        int j1 = cch * 256 + tid;
        float acc[ROWS];
#pragma unroll
        for (int r = 0; r < ROWS; r++) acc[r] = 0.f;
        for (int i = 0; i < D_; i += 4) {
            float w0 = W1[(size_t)(i + 0) * FF + j1];
            float w1 = W1[(size_t)(i + 1) * FF + j1];
            float w2 = W1[(size_t)(i + 2) * FF + j1];
            float w3 = W1[(size_t)(i + 3) * FF + j1];
#pragma unroll
            for (int r = 0; r < ROWS; r++) {
                float4 a = *(const float4*)(&Xs[r][i]);
                acc[r] = fmaf(a.x, w0, acc[r]);
                acc[r] = fmaf(a.y, w1, acc[r]);
                acc[r] = fmaf(a.z, w2, acc[r]);
                acc[r] = fmaf(a.w, w3, acc[r]);
            }
        }
        float bb = bfc1[l * FF + j1];
#pragma unroll
        for (int r = 0; r < ROWS; r++) {
            float v = acc[r] + bb;
            Hs[r][j1] = v * 0.5f * (1.f + erff(v * 0.70710678118654752f));   // exact gelu
        }
    }
    __syncthreads();
    float acc2[ROWS];
#pragma unroll
    for (int r = 0; r < ROWS; r++) acc2[r] = 0.f;
    for (int i = 0; i < FF; i += 4) {
        float w0 = W2[(size_t)(i + 0) * D_ + tid];
        float w1 = W2[(size_t)(i + 1) * D_ + tid];
        float w2 = W2[(size_t)(i + 2) * D_ + tid];
        float w3 = W2[(size_t)(i + 3) * D_ + tid];
#pragma unroll
        for (int r = 0; r < ROWS; r++) {
            float4 hh = *(const float4*)(&Hs[r][i]);
            acc2[r] = fmaf(hh.x, w0, acc2[r]);
            acc2[r] = fmaf(hh.y, w1, acc2[r]);
            acc2[r] = fmaf(hh.z, w2, acc2[r]);
            acc2[r] = fmaf(hh.w, w3, acc2[r]);
        }
    }
    float bj = bfc2[l * D_ + tid], gj = g4[l * D_ + tid], bej = b4[l * D_ + tid];
    __syncthreads();
#pragma unroll
    for (int r = 0; r < ROWS; r++) Hs[r][tid] = acc2[r] + bj + Xs[r][tid];
    __syncthreads();
    for (int r = 0; r < ROWS; r++) {
        int t = rt * ROWS + r;
        if (t >= TVT) continue;        // uniform across block
        float v = Hs[r][tid];
        float a = v, sq = v * v;
        blockReduce2_256(a, sq, red, tid);
        float mean = a * (1.f / D_);
        float var = sq * (1.f / D_) - mean * mean;
        float ov = (v - mean) * rsqrtf(var + 1e-5f) * gj + bej;
        if (t < NVT) out_sel[((size_t)b * 32 + l * NVT + t) * D_ + tid] = ov;
        else         out_seen[(((size_t)b * NLV + l) * NSEEN + (t - NVT)) * D_ + tid] = ov;
    }
}

// ---------------- launch ----------------

extern "C" void kernel_launch(void* const* d_in, const int* in_sizes, int n_in,
                              void* d_out, int out_size, void* d_ws, size_t ws_size,
                              hipStream_t stream)
{
    const float* src      = (const float*)d_in[0];
    const float* pos      = (const float*)d_in[1];
    const float* refp     = (const float*)d_in[2];
    const float* seen     = (const float*)d_in[5];
    const float* sel      = (const float*)d_in[6];
    const float* w_off    = (const float*)d_in[7];
    const float* b_off    = (const float*)d_in[8];
    const float* w_attn   = (const float*)d_in[9];
    const float* b_attn   = (const float*)d_in[10];
    const float* w_val    = (const float*)d_in[11];
    const float* b_val    = (const float*)d_in[12];
    const float* w_out    = (const float*)d_in[13];
    const float* b_out    = (const float*)d_in[14];
    const float* g1       = (const float*)d_in[15];
    const float* be1      = (const float*)d_in[16];
    const float* w_ff1    = (const float*)d_in[17];
    const float* b_ff1    = (const float*)d_in[18];
    const float* w_ff2    = (const float*)d_in[19];
    const float* b_ff2    = (const float*)d_in[20];
    const float* g2       = (const float*)d_in[21];
    const float* be2      = (const float*)d_in[22];
    const float* vt_wqkv  = (const float*)d_in[23];
    const float* vt_bqkv  = (const float*)d_in[24];
    const float* vt_wproj = (const float*)d_in[25];
    const float* vt_bproj = (const float*)d_in[26];
    const float* vt_g3    = (const float*)d_in[27];
    const float* vt_b3    = (const float*)d_in[28];
    const float* vt_g4    = (const float*)d_in[29];
    const float* vt_b4    = (const float*)d_in[30];
    const float* vt_wfc1  = (const float*)d_in[31];
    const float* vt_bfc1  = (const float*)d_in[32];
    const float* vt_wfc2  = (const float*)d_in[33];
    const float* vt_bfc2  = (const float*)d_in[34];

    float* ws = (float*)d_ws;
    float* value = ws;                        // 11,157,504
    float* offb  = ws + 11157504;             // 11,157,504
    float* wall  = ws + 22315008;             // 16,736,256
    float* attn  = ws + 39051264;             // 11,157,504
    float* xtail = ws + 50208768;             //     16,384
    float* qkv   = ws + 50225152;             //    442,368
    float* obuf  = ws + 50667520;             //    147,456
    float* vts2  = ws + 50814976;             //    147,456

    float* outx     = (float*)d_out;
    float* out_seen = outx + (size_t)BB * LSP * D_;           // 11,141,120
    float* out_sel  = out_seen + (size_t)BB * NLV * NSEEN * D_; // +131,072

    const int NRT = NBQ / ROWS;  // 2724

    gemm256_k<0><<<NRT, 256, 0, stream>>>(src, pos, sel, w_val, b_val, value);
    gemm256_k<1><<<NRT, 256, 0, stream>>>(src, pos, sel, w_off, b_off, offb);
    gemm_logits_k<<<NRT, 384, 0, stream>>>(src, pos, sel, w_attn, b_attn, wall);
    sample_k<<<NBQ, 256, 0, stream>>>(value, offb, wall, refp, attn);
    gemm_out_ln1_k<<<NRT, 256, 0, stream>>>(attn, w_out, b_out, src, sel, g1, be1, outx, xtail);
    ffn_ln2_k<<<NRT, 256, 0, stream>>>(w_ff1, b_ff1, w_ff2, b_ff2, g2, be2, outx, xtail);
    vt_qkv_k<<<dim3(5, 3, 8), 256, 0, stream>>>(xtail, seen, vt_wqkv, vt_bqkv, qkv);
    vt_attn_k<<<BB * NLV * NH, 128, 0, stream>>>(qkv, obuf);
    vt_proj_ln3_k<<<dim3(5, 1, 8), 256, 0, stream>>>(obuf, vt_wproj, vt_bproj, xtail, seen, vt_g3, vt_b3, vts2);
    vt_mlp_ln4_k<<<dim3(5, 1, 8), 256, 0, stream>>>(vts2, vt_wfc1, vt_bfc1, vt_wfc2, vt_bfc2, vt_g4, vt_b4, out_seen, out_sel);
}

// Round 2
// 1330.497 us; speedup vs baseline: 2.4448x; 2.4448x over previous
//
#include <hip/hip_runtime.h>
#include <math.h>

#define D_    256
#define NH    8
#define DHD   32
#define NLV   4
#define NPT   4
#define NVT   8
#define NSEEN 64
#define TVT   72
#define FF    1024
#define BB    2
#define LSP   21760
#define LQ    21792
#define NBQ   (BB*LQ)      // 43584
#define ROWS  16

typedef __attribute__((ext_vector_type(8))) short short8;
typedef __attribute__((ext_vector_type(4))) float f32x4;

__device__ __forceinline__ unsigned short f2bf(float f)
{
    unsigned int u = __float_as_uint(f);
    u += 0x7fffu + ((u >> 16) & 1u);
    return (unsigned short)(u >> 16);
}

// ---------------- weight transpose+convert: Wt[n][k] = bf16(W[k][n]) ----------------
__global__ __launch_bounds__(256) void cvt_wT_k(const float* __restrict__ W, unsigned short* __restrict__ Wt,
                                                int K, int N)
{
    __shared__ float T[32][33];
    const int tid = threadIdx.x;
    const int n0 = blockIdx.x * 32, k0 = blockIdx.y * 32;
    const int tx = tid & 31, ty = tid >> 5;   // ty 0..7
#pragma unroll
    for (int s = 0; s < 4; s++)
        T[ty + 8 * s][tx] = W[(size_t)(k0 + ty + 8 * s) * N + n0 + tx];
    __syncthreads();
#pragma unroll
    for (int s = 0; s < 4; s++)
        Wt[(size_t)(n0 + ty + 8 * s) * K + k0 + tx] = f2bf(T[tx][ty + 8 * s]);
}

// ---------------- input concat+convert ----------------
__global__ __launch_bounds__(256) void cvt_in_k(const float* __restrict__ src, const float* __restrict__ pos,
                                                const float* __restrict__ sel, unsigned short* __restrict__ a0,
                                                unsigned short* __restrict__ a1)
{
    size_t idx = ((size_t)blockIdx.x * 256 + threadIdx.x) * 4;
    int row = (int)(idx >> 8), c = (int)(idx & 255);
    int b = row / LQ, i = row - b * LQ;
    f32x4 v0, v1;
    if (i < LSP) {
        size_t g = ((size_t)b * LSP + i) * 256 + c;
        v0 = *(const f32x4*)(src + g);
        f32x4 p = *(const f32x4*)(pos + g);
        v1 = v0 + p;
    } else {
        size_t g = ((size_t)b * 32 + (i - LSP)) * 256 + c;
        v0 = *(const f32x4*)(sel + g);
        v1 = v0;
    }
    uint2 r0, r1;
    r0.x = (unsigned)f2bf(v0.x) | ((unsigned)f2bf(v0.y) << 16);
    r0.y = (unsigned)f2bf(v0.z) | ((unsigned)f2bf(v0.w) << 16);
    r1.x = (unsigned)f2bf(v1.x) | ((unsigned)f2bf(v1.y) << 16);
    r1.y = (unsigned)f2bf(v1.z) | ((unsigned)f2bf(v1.w) << 16);
    *(uint2*)(a0 + idx) = r0;
    *(uint2*)(a1 + idx) = r1;
}

// x (outx/xtail f32) -> xb bf16
__global__ __launch_bounds__(256) void cvt_x_k(const float* __restrict__ xsp, const float* __restrict__ xtail,
                                               unsigned short* __restrict__ xb)
{
    size_t idx = ((size_t)blockIdx.x * 256 + threadIdx.x) * 4;
    int row = (int)(idx >> 8), c = (int)(idx & 255);
    int b = row / LQ, i = row - b * LQ;
    f32x4 v;
    if (i < LSP) v = *(const f32x4*)(xsp + ((size_t)b * LSP + i) * 256 + c);
    else         v = *(const f32x4*)(xtail + ((size_t)b * 32 + (i - LSP)) * 256 + c);
    uint2 r;
    r.x = (unsigned)f2bf(v.x) | ((unsigned)f2bf(v.y) << 16);
    r.y = (unsigned)f2bf(v.z) | ((unsigned)f2bf(v.w) << 16);
    *(uint2*)(xb + idx) = r;
}

// ---------------- MFMA GEMM: C[M][N] = A[M][K](bf16) @ B[N][K](bf16)^T + bias ----------------
// 64x64 tile, 4 waves, each wave 32x32 as 2x2 16x16x32 frags.
template<int MODE>   // 0: Cf = acc+bias (f32)   1: Cb = bf16(relu(acc+bias))
__global__ __launch_bounds__(256) void mfma_gemm_k(const unsigned short* __restrict__ A,
                                                   const unsigned short* __restrict__ B,
                                                   const float* __restrict__ bias,
                                                   float* __restrict__ Cf, unsigned short* __restrict__ Cb,
                                                   int K, int N)
{
    __shared__ __align__(16) short As[2048];   // [fr4][kg4][r16][8]
    __shared__ __align__(16) short Bs[2048];
    const int tid = threadIdx.x;
    const int row0 = blockIdx.x * 64;
    const int n0 = blockIdx.y * 64;
    const int w = tid >> 6, lane = tid & 63;
    const int r16 = lane & 15, q = lane >> 4;

    const unsigned short* gap = A + (size_t)(row0 + w * 16 + r16) * K + q * 8;
    const unsigned short* gbp = B + (size_t)(n0 + w * 16 + r16) * K + q * 8;
    short* sa = As + ((w * 4 + q) * 16 + r16) * 8;
    short* sb = Bs + ((w * 4 + q) * 16 + r16) * 8;

    const int wr2 = (w >> 1) * 2;   // A frag-block base (0 or 2)
    const int wc2 = (w & 1) * 2;    // B frag-block base

    f32x4 acc[2][2] = {};
    for (int k0 = 0; k0 < K; k0 += 32) {
        *(short8*)sa = *(const short8*)(gap + k0);
        *(short8*)sb = *(const short8*)(gbp + k0);
        __syncthreads();
        short8 af0 = *(const short8*)(As + (((wr2 + 0) * 4 + q) * 16 + r16) * 8);
        short8 af1 = *(const short8*)(As + (((wr2 + 1) * 4 + q) * 16 + r16) * 8);
        short8 bf0 = *(const short8*)(Bs + (((wc2 + 0) * 4 + q) * 16 + r16) * 8);
        short8 bf1 = *(const short8*)(Bs + (((wc2 + 1) * 4 + q) * 16 + r16) * 8);
        acc[0][0] = __builtin_amdgcn_mfma_f32_16x16x32_bf16(af0, bf0, acc[0][0], 0, 0, 0);
        acc[0][1] = __builtin_amdgcn_mfma_f32_16x16x32_bf16(af0, bf1, acc[0][1], 0, 0, 0);
        acc[1][0] = __builtin_amdgcn_mfma_f32_16x16x32_bf16(af1, bf0, acc[1][0], 0, 0, 0);
        acc[1][1] = __builtin_amdgcn_mfma_f32_16x16x32_bf16(af1, bf1, acc[1][1], 0, 0, 0);
        __syncthreads();
    }
#pragma unroll
    for (int fm = 0; fm < 2; fm++) {
#pragma unroll
        for (int fn = 0; fn < 2; fn++) {
            int col = n0 + (w & 1) * 32 + fn * 16 + r16;
            float bj = bias[col];
#pragma unroll
            for (int i = 0; i < 4; i++) {
                int row = row0 + (w >> 1) * 32 + fm * 16 + q * 4 + i;
                float v = acc[fm][fn][i] + bj;
                if (MODE == 0) Cf[(size_t)row * N + col] = v;
                else           Cb[(size_t)row * N + col] = f2bf(fmaxf(v, 0.f));
            }
        }
    }
}

// ---------------- softmax over groups of 48, in place on wall [NBQ][384] ----------------
__global__ __launch_bounds__(384) void softmax48_k(float* __restrict__ wall)
{
    __shared__ float Ls[384];
    __shared__ float Es[384];
    const int row = blockIdx.x, j = threadIdx.x;
    float v = wall[(size_t)row * 384 + j];
    Ls[j] = v;
    __syncthreads();
    const int g0 = (j / 48) * 48;
    float m = -1e30f;
    for (int k = 0; k < 48; k++) m = fmaxf(m, Ls[g0 + k]);
    float e = __expf(v - m);
    Es[j] = e;
    __syncthreads();
    float s = 0.f;
    for (int k = 0; k < 48; k++) s += Es[g0 + k];
    wall[(size_t)row * 384 + j] = e / s;
}

// ---------------- residual + LayerNorm: dst = LN(y + resid) ----------------
// one wave per row; 4 rows per block
__global__ __launch_bounds__(256) void resid_ln_k(const float* __restrict__ y, const float* __restrict__ rsp,
                                                  const float* __restrict__ rtail, const float* __restrict__ g,
                                                  const float* __restrict__ be, float* __restrict__ dsp,
                                                  float* __restrict__ dtail)
{
    const int row = blockIdx.x * 4 + (threadIdx.x >> 6);
    const int lane = threadIdx.x & 63;
    const int b = row / LQ, i = row - b * LQ;
    f32x4 yv = *(const f32x4*)(y + (size_t)row * 256 + lane * 4);
    f32x4 rv;
    size_t didx;
    float* dbase;
    if (i < LSP) { size_t gidx = ((size_t)b * LSP + i) * 256; rv = *(const f32x4*)(rsp + gidx + lane * 4); dbase = dsp; didx = gidx; }
    else         { size_t gidx = ((size_t)b * 32 + (i - LSP)) * 256; rv = *(const f32x4*)(rtail + gidx + lane * 4); dbase = dtail; didx = gidx; }
    float t0 = yv.x + rv.x, t1 = yv.y + rv.y, t2 = yv.z + rv.z, t3 = yv.w + rv.w;
    float s = t0 + t1 + t2 + t3;
    float ss = t0 * t0 + t1 * t1 + t2 * t2 + t3 * t3;
#pragma unroll
    for (int off = 32; off; off >>= 1) {
        s += __shfl_xor(s, off, 64);
        ss += __shfl_xor(ss, off, 64);
    }
    float mean = s * (1.f / 256.f);
    float var = ss * (1.f / 256.f) - mean * mean;
    float rstd = rsqrtf(var + 1e-5f);
    int c = lane * 4;
    f32x4 gv = *(const f32x4*)(g + c);
    f32x4 bv = *(const f32x4*)(be + c);
    f32x4 o;
    o.x = (t0 - mean) * rstd * gv.x + bv.x;
    o.y = (t1 - mean) * rstd * gv.y + bv.y;
    o.z = (t2 - mean) * rstd * gv.z + bv.z;
    o.w = (t3 - mean) * rstd * gv.w + bv.w;
    *(f32x4*)(dbase + didx + c) = o;
}

// ---------------- deformable sampling + vt-token attention mix (bf16 out) ----------------
__global__ __launch_bounds__(256) void sample_k(const float* __restrict__ value, const float* __restrict__ offb,
                                                const float* __restrict__ wall, const float* __restrict__ refp,
                                                unsigned short* __restrict__ attn)
{
    __shared__ float OF[256];
    __shared__ float WA[384];
    __shared__ float RP[8];
    const int bq = blockIdx.x;
    const int b = bq / LQ;
    const int tid = threadIdx.x;
    OF[tid] = offb[(size_t)bq * 256 + tid];
    for (int idx = tid; idx < 384; idx += 256) WA[idx] = wall[(size_t)bq * 384 + idx];
    if (tid < 8) RP[tid] = refp[(size_t)bq * 8 + tid];
    __syncthreads();
    const int h = tid >> 5, d = tid & 31;
    const size_t vbase = ((size_t)b * LQ) * 256 + (size_t)(h * 32 + d);
    float acc = 0.f;
    const int HL[4] = {128, 64, 32, 16};
    const int S0[4] = {0, 16384, 20480, 21504};
#pragma unroll
    for (int l = 0; l < NLV; l++) {
        const int Wl = HL[l], Hl = HL[l];
        const int s0 = S0[l];
        float rx = RP[l * 2 + 0] * (float)Wl - 0.5f;
        float ry = RP[l * 2 + 1] * (float)Hl - 0.5f;
#pragma unroll
        for (int p = 0; p < NPT; p++) {
            float x = rx + OF[h * 32 + l * 8 + p * 2 + 0];
            float y = ry + OF[h * 32 + l * 8 + p * 2 + 1];
            float wl = WA[h * 48 + l * 12 + p];
            float x0f = floorf(x), y0f = floorf(y);
            int x0 = (int)x0f, y0 = (int)y0f;
            float fx = x - x0f, fy = y - y0f;
            float w00 = (1.f - fx) * (1.f - fy) * wl;
            float w01 = fx * (1.f - fy) * wl;
            float w10 = (1.f - fx) * fy * wl;
            float w11 = fx * fy * wl;
            bool xok0 = (x0 >= 0) && (x0 < Wl);
            bool xok1 = (x0 + 1 >= 0) && (x0 + 1 < Wl);
            bool yok0 = (y0 >= 0) && (y0 < Hl);
            bool yok1 = (y0 + 1 >= 0) && (y0 + 1 < Hl);
            if (xok0 && yok0) acc += w00 * value[vbase + (size_t)(s0 + y0 * Wl + x0) * 256];
            if (xok1 && yok0) acc += w01 * value[vbase + (size_t)(s0 + y0 * Wl + x0 + 1) * 256];
            if (xok0 && yok1) acc += w10 * value[vbase + (size_t)(s0 + (y0 + 1) * Wl + x0) * 256];
            if (xok1 && yok1) acc += w11 * value[vbase + (size_t)(s0 + (y0 + 1) * Wl + x0 + 1) * 256];
        }
    }
#pragma unroll
    for (int l = 0; l < NLV; l++) {
#pragma unroll
        for (int v = 0; v < NVT; v++) {
            acc += WA[h * 48 + l * 12 + 4 + v] * value[vbase + (size_t)(LSP + l * NVT + v) * 256];
        }
    }
    attn[(size_t)bq * 256 + tid] = f2bf(acc);
}

// ---------------- VT transformer layers (unchanged, small) ----------------

__device__ __forceinline__ void blockReduce2_256(float& a, float& b, float* red, int tid)
{
#pragma unroll
    for (int off = 32; off > 0; off >>= 1) {
        a += __shfl_down(a, off, 64);
        b += __shfl_down(b, off, 64);
    }
    __syncthreads();
    int wid = tid >> 6;
    if ((tid & 63) == 0) { red[wid] = a; red[wid + 4] = b; }
    __syncthreads();
    a = red[0] + red[1] + red[2] + red[3];
    b = red[4] + red[5] + red[6] + red[7];
}

__device__ __forceinline__ float fetch_vts(const float* __restrict__ xtail, const float* __restrict__ seen,
                                           int b, int l, int t, int c)
{
    return (t < NVT) ? xtail[((size_t)b * 32 + l * NVT + t) * D_ + c]
                     : seen[(((size_t)b * NLV + l) * NSEEN + (t - NVT)) * D_ + c];
}

__global__ __launch_bounds__(256) void vt_qkv_k(const float* __restrict__ xtail, const float* __restrict__ seen,
                                                const float* __restrict__ wqkv, const float* __restrict__ bqkv,
                                                float* __restrict__ qkv)
{
    const int rt = blockIdx.x, cb = blockIdx.y, z = blockIdx.z;
    const int b = z >> 2, l = z & 3;
    __shared__ float As[ROWS][D_];
    const int tid = threadIdx.x;
    for (int idx = tid; idx < ROWS * D_; idx += 256) {
        int r = idx >> 8, c = idx & 255;
        int t = rt * ROWS + r;
        As[r][c] = (t < TVT) ? fetch_vts(xtail, seen, b, l, t, c) : 0.f;
    }
    __syncthreads();
    const float* W = wqkv + (size_t)l * D_ * 768;
    const int j = cb * 256 + tid;
    float acc[ROWS];
#pragma unroll
    for (int r = 0; r < ROWS; r++) acc[r] = 0.f;
    for (int i = 0; i < D_; i += 4) {
        float w0 = W[(size_t)(i + 0) * 768 + j];
        float w1 = W[(size_t)(i + 1) * 768 + j];
        float w2 = W[(size_t)(i + 2) * 768 + j];
        float w3 = W[(size_t)(i + 3) * 768 + j];
#pragma unroll
        for (int r = 0; r < ROWS; r++) {
            float4 a = *(const float4*)(&As[r][i]);
            acc[r] = fmaf(a.x, w0, acc[r]);
            acc[r] = fmaf(a.y, w1, acc[r]);
            acc[r] = fmaf(a.z, w2, acc[r]);
            acc[r] = fmaf(a.w, w3, acc[r]);
        }
    }
    float bj = bqkv[l * 768 + j];
#pragma unroll
    for (int r = 0; r < ROWS; r++) {
        int t = rt * ROWS + r;
        if (t < TVT) qkv[((size_t)z * TVT + t) * 768 + j] = acc[r] + bj;
    }
}

__global__ __launch_bounds__(128) void vt_attn_k(const float* __restrict__ qkv, float* __restrict__ o)
{
    const int z = blockIdx.x;
    const int h = z & 7, bl = z >> 3;
    __shared__ float Qs[TVT][33];
    __shared__ float Ks[TVT][DHD];
    __shared__ float Vs[TVT][DHD];
    __shared__ float Ss[TVT][73];
    const int tid = threadIdx.x;
    for (int idx = tid; idx < TVT * DHD; idx += 128) {
        int t = idx >> 5, d = idx & 31;
        const float* base = qkv + ((size_t)bl * TVT + t) * 768 + h * DHD + d;
        Qs[t][d] = base[0];
        Ks[t][d] = base[256];
        Vs[t][d] = base[512];
    }
    __syncthreads();
    if (tid < TVT) {
        const float scale = 0.17677669529663687f;
        float qr[DHD];
#pragma unroll
        for (int d = 0; d < DHD; d++) qr[d] = Qs[tid][d];
        float m = -1e30f;
        for (int k = 0; k < TVT; k++) {
            float s = 0.f;
#pragma unroll
            for (int d = 0; d < DHD; d++) s = fmaf(qr[d], Ks[k][d], s);
            s *= scale;
            Ss[tid][k] = s;
            m = fmaxf(m, s);
        }
        float sum = 0.f;
        for (int k = 0; k < TVT; k++) {
            float e = __expf(Ss[tid][k] - m);
            Ss[tid][k] = e;
            sum += e;
        }
        float inv = 1.f / sum;
        for (int d = 0; d < DHD; d++) {
            float acc = 0.f;
            for (int k = 0; k < TVT; k++) acc = fmaf(Ss[tid][k], Vs[k][d], acc);
            o[((size_t)bl * TVT + tid) * D_ + h * DHD + d] = acc * inv;
        }
    }
}

__global__ __launch_bounds__(256) void vt_proj_ln3_k(const float* __restrict__ obuf, const float* __restrict__ wproj,
                                                     const float* __restrict__ bproj, const float* __restrict__ xtail,
                                                     const float* __restrict__ seen, const float* __restrict__ g3,
                                                     const float* __restrict__ b3, float* __restrict__ vts2)
{
    const int rt = blockIdx.x, z = blockIdx.z;
    const int b = z >> 2, l = z & 3;
    __shared__ float As[ROWS][D_];
    __shared__ float Ts[ROWS][D_];
    __shared__ float red[8];
    const int tid = threadIdx.x;
    for (int idx = tid; idx < ROWS * D_; idx += 256) {
        int r = idx >> 8, c = idx & 255;
        int t = rt * ROWS + r;
        As[r][c] = (t < TVT) ? obuf[((size_t)z * TVT + t) * D_ + c] : 0.f;
    }
    __syncthreads();
    const float* W = wproj + (size_t)l * D_ * D_;
    const int j = tid;
    float acc[ROWS];
#pragma unroll
    for (int r = 0; r < ROWS; r++) acc[r] = 0.f;
    for (int i = 0; i < D_; i += 4) {
        float w0 = W[(size_t)(i + 0) * D_ + j];
        float w1 = W[(size_t)(i + 1) * D_ + j];
        float w2 = W[(size_t)(i + 2) * D_ + j];
        float w3 = W[(size_t)(i + 3) * D_ + j];
#pragma unroll
        for (int r = 0; r < ROWS; r++) {
            float4 a = *(const float4*)(&As[r][i]);
            acc[r] = fmaf(a.x, w0, acc[r]);
            acc[r] = fmaf(a.y, w1, acc[r]);
            acc[r] = fmaf(a.z, w2, acc[r]);
            acc[r] = fmaf(a.w, w3, acc[r]);
        }
    }
    float bj = bproj[l * D_ + j];
#pragma unroll
    for (int r = 0; r < ROWS; r++) {
        int t = rt * ROWS + r;
        if (t < TVT) Ts[r][j] = acc[r] + bj + fetch_vts(xtail, seen, b, l, t, j);
    }
    __syncthreads();
    float gj = g3[l * D_ + j], bej = b3[l * D_ + j];
    for (int r = 0; r < ROWS; r++) {
        int t = rt * ROWS + r;
        if (t >= TVT) continue;
        float v = Ts[r][j];
        float a = v, sq = v * v;
        blockReduce2_256(a, sq, red, tid);
        float mean = a * (1.f / D_);
        float var = sq * (1.f / D_) - mean * mean;
        vts2[((size_t)z * TVT + t) * D_ + j] = (v - mean) * rsqrtf(var + 1e-5f) * gj + bej;
    }
}

__global__ __launch_bounds__(256) void vt_mlp_ln4_k(const float* __restrict__ vts2, const float* __restrict__ wfc1,
                                                    const float* __restrict__ bfc1, const float* __restrict__ wfc2,
                                                    const float* __restrict__ bfc2, const float* __restrict__ g4,
                                                    const float* __restrict__ b4, float* __restrict__ out_seen,
                                                    float* __restrict__ out_sel)
{
    const int rt = blockIdx.x, z = blockIdx.z;
    const int b = z >> 2, l = z & 3;
    __shared__ float Xs[ROWS][D_];
    __shared__ float Hs[ROWS][FF];
    __shared__ float red[8];
    const int tid = threadIdx.x;
    for (int idx = tid; idx < ROWS * D_; idx += 256) {
        int r = idx >> 8, c = idx & 255;
        int t = rt * ROWS + r;
        Xs[r][c] = (t < TVT) ? vts2[((size_t)z * TVT + t) * D_ + c] : 0.f;
    }
    __syncthreads();
    const float* W1 = wfc1 + (size_t)l * D_ * FF;
    const float* W2 = wfc2 + (size_t)l * FF * D_;
    for (int cch = 0; cch < 4; cch++) {
        int j1 = cch * 256 + tid;
        float acc[ROWS];
#pragma unroll
        for (int r = 0; r < ROWS; r++) acc[r] = 0.f;
        for (int i = 0; i < D_; i += 4) {
            float w0 = W1[(size_t)(i + 0) * FF + j1];
            float w1 = W1[(size_t)(i + 1) * FF + j1];
            float w2 = W1[(size_t)(i + 2) * FF + j1];
            float w3 = W1[(size_t)(i + 3) * FF + j1];
#pragma unroll
            for (int r = 0; r < ROWS; r++) {
                float4 a = *(const float4*)(&Xs[r][i]);
                acc[r] = fmaf(a.x, w0, acc[r]);
                acc[r] = fmaf(a.y, w1, acc[r]);
                acc[r] = fmaf(a.z, w2, acc[r]);
                acc[r] = fmaf(a.w, w3, acc[r]);
            }
        }
        float bb = bfc1[l * FF + j1];
#pragma unroll
        for (int r = 0; r < ROWS; r++) {
            float v = acc[r] + bb;
            Hs[r][j1] = v * 0.5f * (1.f + erff(v * 0.70710678118654752f));
        }
    }
    __syncthreads();
    float acc2[ROWS];
#pragma unroll
    for (int r = 0; r < ROWS; r++) acc2[r] = 0.f;
    for (int i = 0; i < FF; i += 4) {
        float w0 = W2[(size_t)(i + 0) * D_ + tid];
        float w1 = W2[(size_t)(i + 1) * D_ + tid];
        float w2 = W2[(size_t)(i + 2) * D_ + tid];
        float w3 = W2[(size_t)(i + 3) * D_ + tid];
#pragma unroll
        for (int r = 0; r < ROWS; r++) {
            float4 hh = *(const float4*)(&Hs[r][i]);
            acc2[r] = fmaf(hh.x, w0, acc2[r]);
            acc2[r] = fmaf(hh.y, w1, acc2[r]);
            acc2[r] = fmaf(hh.z, w2, acc2[r]);
            acc2[r] = fmaf(hh.w, w3, acc2[r]);
        }
    }
    float bj = bfc2[l * D_ + tid], gj = g4[l * D_ + tid], bej = b4[l * D_ + tid];
    __syncthreads();
#pragma unroll
    for (int r = 0; r < ROWS; r++) Hs[r][tid] = acc2[r] + bj + Xs[r][tid];
    __syncthreads();
    for (int r = 0; r < ROWS; r++) {
        int t = rt * ROWS + r;
        if (t >= TVT) continue;
        float v = Hs[r][tid];
        float a = v, sq = v * v;
        blockReduce2_256(a, sq, red, tid);
        float mean = a * (1.f / D_);
        float var = sq * (1.f / D_) - mean * mean;
        float ov = (v - mean) * rsqrtf(var + 1e-5f) * gj + bej;
        if (t < NVT) out_sel[((size_t)b * 32 + l * NVT + t) * D_ + tid] = ov;
        else         out_seen[(((size_t)b * NLV + l) * NSEEN + (t - NVT)) * D_ + tid] = ov;
    }
}

// ---------------- launch ----------------

extern "C" void kernel_launch(void* const* d_in, const int* in_sizes, int n_in,
                              void* d_out, int out_size, void* d_ws, size_t ws_size,
                              hipStream_t stream)
{
    const float* src      = (const float*)d_in[0];
    const float* pos      = (const float*)d_in[1];
    const float* refp     = (const float*)d_in[2];
    const float* seen     = (const float*)d_in[5];
    const float* sel      = (const float*)d_in[6];
    const float* w_off    = (const float*)d_in[7];
    const float* b_off    = (const float*)d_in[8];
    const float* w_attn   = (const float*)d_in[9];
    const float* b_attn   = (const float*)d_in[10];
    const float* w_val    = (const float*)d_in[11];
    const float* b_val    = (const float*)d_in[12];
    const float* w_out    = (const float*)d_in[13];
    const float* b_out    = (const float*)d_in[14];
    const float* g1       = (const float*)d_in[15];
    const float* be1      = (const float*)d_in[16];
    const float* w_ff1    = (const float*)d_in[17];
    const float* b_ff1    = (const float*)d_in[18];
    const float* w_ff2    = (const float*)d_in[19];
    const float* b_ff2    = (const float*)d_in[20];
    const float* g2       = (const float*)d_in[21];
    const float* be2      = (const float*)d_in[22];
    const float* vt_wqkv  = (const float*)d_in[23];
    const float* vt_bqkv  = (const float*)d_in[24];
    const float* vt_wproj = (const float*)d_in[25];
    const float* vt_bproj = (const float*)d_in[26];
    const float* vt_g3    = (const float*)d_in[27];
    const float* vt_b3    = (const float*)d_in[28];
    const float* vt_g4    = (const float*)d_in[29];
    const float* vt_b4    = (const float*)d_in[30];
    const float* vt_wfc1  = (const float*)d_in[31];
    const float* vt_bfc1  = (const float*)d_in[32];
    const float* vt_wfc2  = (const float*)d_in[33];
    const float* vt_bfc2  = (const float*)d_in[34];

    float* ws = (float*)d_ws;
    // region map (f32 word offsets); lifetimes overlap deliberately:
    float* value = ws;                               // [0, 11157504)   later: y, y2, then qkv/obuf/vts2
    float* offb  = ws + 11157504;                    // [11157504, 22315008)  later: hb (bf16, spans into wall)
    float* wall  = ws + 22315008;                    // [22315008, 39051264)
    unsigned short* a0b  = (unsigned short*)(ws + 39051264);  // 11157504 bf16; later: attn
    unsigned short* a1b  = (unsigned short*)(ws + 44630016);  // 11157504 bf16; later: xb
    unsigned short* attn = (unsigned short*)(ws + 39051264);
    unsigned short* xb   = (unsigned short*)(ws + 44630016);
    unsigned short* hb   = (unsigned short*)(ws + 11157504);  // 44630016 bf16 over offb+wall
    float* y     = ws;                               // over value
    float* y2    = ws;                               // over value (after y dead)
    float* qkv   = ws;                               // VT phase over region A
    float* obuf  = ws + 442368;
    float* vts2  = ws + 589824;
    float* xtail = ws + 50208768;                    // 16384
    unsigned short* wtb = (unsigned short*)(ws + 50225152);   // 819200 bf16 total
    unsigned short* wvalT  = wtb;                    // 256x256
    unsigned short* woffT  = wtb + 65536;            // 256x256
    unsigned short* wattnT = wtb + 131072;           // 384x256
    unsigned short* woutT  = wtb + 229376;           // 256x256
    unsigned short* wff1T  = wtb + 294912;           // 1024x256
    unsigned short* wff2T  = wtb + 557056;           // 256x1024

    float* outx     = (float*)d_out;
    float* out_seen = outx + (size_t)BB * LSP * D_;
    float* out_sel  = out_seen + (size_t)BB * NLV * NSEEN * D_;

    // 1. weight converts
    cvt_wT_k<<<dim3(8, 8),  256, 0, stream>>>(w_val,  wvalT,  256, 256);
    cvt_wT_k<<<dim3(8, 8),  256, 0, stream>>>(w_off,  woffT,  256, 256);
    cvt_wT_k<<<dim3(12, 8), 256, 0, stream>>>(w_attn, wattnT, 256, 384);
    cvt_wT_k<<<dim3(8, 8),  256, 0, stream>>>(w_out,  woutT,  256, 256);
    cvt_wT_k<<<dim3(32, 8), 256, 0, stream>>>(w_ff1,  wff1T,  256, 1024);
    cvt_wT_k<<<dim3(8, 32), 256, 0, stream>>>(w_ff2,  wff2T,  1024, 256);
    // 2. input converts
    cvt_in_k<<<10896, 256, 0, stream>>>(src, pos, sel, a0b, a1b);
    // 3. projection GEMMs
    mfma_gemm_k<0><<<dim3(681, 4),  256, 0, stream>>>(a0b, wvalT,  b_val,  value, nullptr, 256, 256);
    mfma_gemm_k<0><<<dim3(681, 4),  256, 0, stream>>>(a1b, woffT,  b_off,  offb,  nullptr, 256, 256);
    mfma_gemm_k<0><<<dim3(681, 6),  256, 0, stream>>>(a1b, wattnT, b_attn, wall,  nullptr, 256, 384);
    softmax48_k<<<NBQ, 384, 0, stream>>>(wall);
    // 4. sampling
    sample_k<<<NBQ, 256, 0, stream>>>(value, offb, wall, refp, attn);
    // 5. out-proj + LN1
    mfma_gemm_k<0><<<dim3(681, 4),  256, 0, stream>>>(attn, woutT, b_out, y, nullptr, 256, 256);
    resid_ln_k<<<NBQ / 4, 256, 0, stream>>>(y, src, sel, g1, be1, outx, xtail);
    // 6. FFN + LN2
    cvt_x_k<<<10896, 256, 0, stream>>>(outx, xtail, xb);
    mfma_gemm_k<1><<<dim3(681, 16), 256, 0, stream>>>(xb, wff1T, b_ff1, nullptr, hb, 256, 1024);
    mfma_gemm_k<0><<<dim3(681, 4),  256, 0, stream>>>(hb, wff2T, b_ff2, y2, nullptr, 1024, 256);
    resid_ln_k<<<NBQ / 4, 256, 0, stream>>>(y2, outx, xtail, g2, be2, outx, xtail);
    // 7. VT chain
    vt_qkv_k<<<dim3(5, 3, 8), 256, 0, stream>>>(xtail, seen, vt_wqkv, vt_bqkv, qkv);
    vt_attn_k<<<BB * NLV * NH, 128, 0, stream>>>(qkv, obuf);
    vt_proj_ln3_k<<<dim3(5, 1, 8), 256, 0, stream>>>(obuf, vt_wproj, vt_bproj, xtail, seen, vt_g3, vt_b3, vts2);
    vt_mlp_ln4_k<<<dim3(5, 1, 8), 256, 0, stream>>>(vts2, vt_wfc1, vt_bfc1, vt_wfc2, vt_bfc2, vt_g4, vt_b4, out_seen, out_sel);
}

// Round 3
// 990.239 us; speedup vs baseline: 3.2848x; 1.3436x over previous
//
#include <hip/hip_runtime.h>
#include <math.h>

#define D_    256
#define NH    8
#define DHD   32
#define NLV   4
#define NPT   4
#define NVT   8
#define NSEEN 64
#define TVT   72
#define FF    1024
#define BB    2
#define LSP   21760
#define LQ    21792
#define NBQ   (BB*LQ)      // 43584
#define ROWS  16

typedef __attribute__((ext_vector_type(8))) short short8;
typedef __attribute__((ext_vector_type(4))) float f32x4;

__device__ __forceinline__ unsigned short f2bf(float f)
{
    unsigned int u = __float_as_uint(f);
    u += 0x7fffu + ((u >> 16) & 1u);
    return (unsigned short)(u >> 16);
}

__device__ __forceinline__ f32x4 bf4(const unsigned short* p)
{
    ushort4 u = *(const ushort4*)p;
    f32x4 r;
    r.x = __uint_as_float((unsigned)u.x << 16);
    r.y = __uint_as_float((unsigned)u.y << 16);
    r.z = __uint_as_float((unsigned)u.z << 16);
    r.w = __uint_as_float((unsigned)u.w << 16);
    return r;
}

// ---------------- weight transpose+convert: Wt[n][k] = bf16(W[k][n]) ----------------
__global__ __launch_bounds__(256) void cvt_wT_k(const float* __restrict__ W, unsigned short* __restrict__ Wt,
                                                int K, int N)
{
    __shared__ float T[32][33];
    const int tid = threadIdx.x;
    const int n0 = blockIdx.x * 32, k0 = blockIdx.y * 32;
    const int tx = tid & 31, ty = tid >> 5;   // ty 0..7
#pragma unroll
    for (int s = 0; s < 4; s++)
        T[ty + 8 * s][tx] = W[(size_t)(k0 + ty + 8 * s) * N + n0 + tx];
    __syncthreads();
#pragma unroll
    for (int s = 0; s < 4; s++)
        Wt[(size_t)(n0 + ty + 8 * s) * K + k0 + tx] = f2bf(T[tx][ty + 8 * s]);
}

// ---------------- input concat+convert ----------------
__global__ __launch_bounds__(256) void cvt_in_k(const float* __restrict__ src, const float* __restrict__ pos,
                                                const float* __restrict__ sel, unsigned short* __restrict__ a0,
                                                unsigned short* __restrict__ a1)
{
    size_t idx = ((size_t)blockIdx.x * 256 + threadIdx.x) * 4;
    int row = (int)(idx >> 8), c = (int)(idx & 255);
    int b = row / LQ, i = row - b * LQ;
    f32x4 v0, v1;
    if (i < LSP) {
        size_t g = ((size_t)b * LSP + i) * 256 + c;
        v0 = *(const f32x4*)(src + g);
        f32x4 p = *(const f32x4*)(pos + g);
        v1 = v0 + p;
    } else {
        size_t g = ((size_t)b * 32 + (i - LSP)) * 256 + c;
        v0 = *(const f32x4*)(sel + g);
        v1 = v0;
    }
    uint2 r0, r1;
    r0.x = (unsigned)f2bf(v0.x) | ((unsigned)f2bf(v0.y) << 16);
    r0.y = (unsigned)f2bf(v0.z) | ((unsigned)f2bf(v0.w) << 16);
    r1.x = (unsigned)f2bf(v1.x) | ((unsigned)f2bf(v1.y) << 16);
    r1.y = (unsigned)f2bf(v1.z) | ((unsigned)f2bf(v1.w) << 16);
    *(uint2*)(a0 + idx) = r0;
    *(uint2*)(a1 + idx) = r1;
}

// ---------------- MFMA GEMM: C[M][N] = A[M][K](bf16) @ B[N][K](bf16)^T + bias ----------------
// 64x64 tile, 4 waves, each wave 32x32 as 2x2 16x16x32 frags.
template<int MODE>   // 0: Cf = acc+bias (f32)   1: Cb = bf16(relu(acc+bias))   2: Cb = bf16(acc+bias)
__global__ __launch_bounds__(256) void mfma_gemm_k(const unsigned short* __restrict__ A,
                                                   const unsigned short* __restrict__ B,
                                                   const float* __restrict__ bias,
                                                   float* __restrict__ Cf, unsigned short* __restrict__ Cb,
                                                   int K, int N)
{
    __shared__ __align__(16) short As[2048];   // [fr4][kg4][r16][8]
    __shared__ __align__(16) short Bs[2048];
    const int tid = threadIdx.x;
    const int row0 = blockIdx.x * 64;
    const int n0 = blockIdx.y * 64;
    const int w = tid >> 6, lane = tid & 63;
    const int r16 = lane & 15, q = lane >> 4;

    const unsigned short* gap = A + (size_t)(row0 + w * 16 + r16) * K + q * 8;
    const unsigned short* gbp = B + (size_t)(n0 + w * 16 + r16) * K + q * 8;
    short* sa = As + ((w * 4 + q) * 16 + r16) * 8;
    short* sb = Bs + ((w * 4 + q) * 16 + r16) * 8;

    const int wr2 = (w >> 1) * 2;   // A frag-block base (0 or 2)
    const int wc2 = (w & 1) * 2;    // B frag-block base

    f32x4 acc[2][2] = {};
    for (int k0 = 0; k0 < K; k0 += 32) {
        *(short8*)sa = *(const short8*)(gap + k0);
        *(short8*)sb = *(const short8*)(gbp + k0);
        __syncthreads();
        short8 af0 = *(const short8*)(As + (((wr2 + 0) * 4 + q) * 16 + r16) * 8);
        short8 af1 = *(const short8*)(As + (((wr2 + 1) * 4 + q) * 16 + r16) * 8);
        short8 bf0 = *(const short8*)(Bs + (((wc2 + 0) * 4 + q) * 16 + r16) * 8);
        short8 bf1 = *(const short8*)(Bs + (((wc2 + 1) * 4 + q) * 16 + r16) * 8);
        acc[0][0] = __builtin_amdgcn_mfma_f32_16x16x32_bf16(af0, bf0, acc[0][0], 0, 0, 0);
        acc[0][1] = __builtin_amdgcn_mfma_f32_16x16x32_bf16(af0, bf1, acc[0][1], 0, 0, 0);
        acc[1][0] = __builtin_amdgcn_mfma_f32_16x16x32_bf16(af1, bf0, acc[1][0], 0, 0, 0);
        acc[1][1] = __builtin_amdgcn_mfma_f32_16x16x32_bf16(af1, bf1, acc[1][1], 0, 0, 0);
        __syncthreads();
    }
#pragma unroll
    for (int fm = 0; fm < 2; fm++) {
#pragma unroll
        for (int fn = 0; fn < 2; fn++) {
            int col = n0 + (w & 1) * 32 + fn * 16 + r16;
            float bj = bias[col];
#pragma unroll
            for (int i = 0; i < 4; i++) {
                int row = row0 + (w >> 1) * 32 + fm * 16 + q * 4 + i;
                float v = acc[fm][fn][i] + bj;
                if (MODE == 0)      Cf[(size_t)row * N + col] = v;
                else if (MODE == 1) Cb[(size_t)row * N + col] = f2bf(fmaxf(v, 0.f));
                else                Cb[(size_t)row * N + col] = f2bf(v);
            }
        }
    }
}

// ---------------- softmax over groups of 48, in place on wall [NBQ][384] ----------------
__global__ __launch_bounds__(384) void softmax48_k(float* __restrict__ wall)
{
    __shared__ float Ls[384];
    __shared__ float Es[384];
    const int row = blockIdx.x, j = threadIdx.x;
    float v = wall[(size_t)row * 384 + j];
    Ls[j] = v;
    __syncthreads();
    const int g0 = (j / 48) * 48;
    float m = -1e30f;
    for (int k = 0; k < 48; k++) m = fmaxf(m, Ls[g0 + k]);
    float e = __expf(v - m);
    Es[j] = e;
    __syncthreads();
    float s = 0.f;
    for (int k = 0; k < 48; k++) s += Es[g0 + k];
    wall[(size_t)row * 384 + j] = e / s;
}

// ---------------- residual + LayerNorm: dst = LN(y + resid); optional bf16 copy ----------------
__global__ __launch_bounds__(256) void resid_ln_k(const float* __restrict__ y, const float* __restrict__ rsp,
                                                  const float* __restrict__ rtail, const float* __restrict__ g,
                                                  const float* __restrict__ be, float* __restrict__ dsp,
                                                  float* __restrict__ dtail, unsigned short* __restrict__ dbf)
{
    const int row = blockIdx.x * 4 + (threadIdx.x >> 6);
    const int lane = threadIdx.x & 63;
    const int b = row / LQ, i = row - b * LQ;
    f32x4 yv = *(const f32x4*)(y + (size_t)row * 256 + lane * 4);
    f32x4 rv;
    size_t didx;
    float* dbase;
    if (i < LSP) { size_t gidx = ((size_t)b * LSP + i) * 256; rv = *(const f32x4*)(rsp + gidx + lane * 4); dbase = dsp; didx = gidx; }
    else         { size_t gidx = ((size_t)b * 32 + (i - LSP)) * 256; rv = *(const f32x4*)(rtail + gidx + lane * 4); dbase = dtail; didx = gidx; }
    float t0 = yv.x + rv.x, t1 = yv.y + rv.y, t2 = yv.z + rv.z, t3 = yv.w + rv.w;
    float s = t0 + t1 + t2 + t3;
    float ss = t0 * t0 + t1 * t1 + t2 * t2 + t3 * t3;
#pragma unroll
    for (int off = 32; off; off >>= 1) {
        s += __shfl_xor(s, off, 64);
        ss += __shfl_xor(ss, off, 64);
    }
    float mean = s * (1.f / 256.f);
    float var = ss * (1.f / 256.f) - mean * mean;
    float rstd = rsqrtf(var + 1e-5f);
    int c = lane * 4;
    f32x4 gv = *(const f32x4*)(g + c);
    f32x4 bv = *(const f32x4*)(be + c);
    f32x4 o;
    o.x = (t0 - mean) * rstd * gv.x + bv.x;
    o.y = (t1 - mean) * rstd * gv.y + bv.y;
    o.z = (t2 - mean) * rstd * gv.z + bv.z;
    o.w = (t3 - mean) * rstd * gv.w + bv.w;
    *(f32x4*)(dbase + didx + c) = o;
    if (dbf) {
        ushort4 ob;
        ob.x = f2bf(o.x); ob.y = f2bf(o.y); ob.z = f2bf(o.z); ob.w = f2bf(o.w);
        *(ushort4*)(dbf + (size_t)row * 256 + c) = ob;
    }
}

// ---------------- deformable sampling + vt mix: one WAVE per query, bf16 value ----------------
// block = 256 threads = 4 queries; lane: h = lane>>3, 4-col chunk c4 = (lane&7)*4
__global__ __launch_bounds__(256) void sample_k(const unsigned short* __restrict__ value,
                                                const float* __restrict__ offb,
                                                const float* __restrict__ wall,
                                                const float* __restrict__ refp,
                                                unsigned short* __restrict__ attn)
{
    __shared__ float OFs[4][256];
    __shared__ float WAs[4][384];
    __shared__ float RPs[4][8];
    const int bq0 = blockIdx.x * 4;
    const int tid = threadIdx.x;
    {
        const float* p = offb + (size_t)bq0 * 256;
        for (int idx = tid; idx < 1024; idx += 256) OFs[idx >> 8][idx & 255] = p[idx];
        const float* pw = wall + (size_t)bq0 * 384;
        for (int idx = tid; idx < 1536; idx += 256) WAs[idx / 384][idx % 384] = pw[idx];
        const float* pr = refp + (size_t)bq0 * 8;
        if (tid < 32) RPs[tid >> 3][tid & 7] = pr[tid];
    }
    __syncthreads();
    const int qs = tid >> 6;
    const int lane = tid & 63;
    const int h = lane >> 3;
    const int c4 = (lane & 7) * 4;
    const int bq = bq0 + qs;
    const int b = bq / LQ;
    const unsigned short* vb = value + ((size_t)b * LQ) * 256 + h * 32 + c4;

    f32x4 acc = {0.f, 0.f, 0.f, 0.f};
    const int HL[4] = {128, 64, 32, 16};
    const int S0[4] = {0, 16384, 20480, 21504};
#pragma unroll
    for (int l = 0; l < NLV; l++) {
        const int Wl = HL[l];
        const int s0 = S0[l];
        float rx = RPs[qs][l * 2 + 0] * (float)Wl - 0.5f;
        float ry = RPs[qs][l * 2 + 1] * (float)Wl - 0.5f;
#pragma unroll
        for (int p = 0; p < NPT; p++) {
            float x = rx + OFs[qs][h * 32 + l * 8 + p * 2 + 0];
            float y = ry + OFs[qs][h * 32 + l * 8 + p * 2 + 1];
            float wgt = WAs[qs][h * 48 + l * 12 + p];
            float x0f = floorf(x), y0f = floorf(y);
            int x0 = (int)x0f, y0 = (int)y0f;
            float fx = x - x0f, fy = y - y0f;
            float vx0 = (x0 >= 0 && x0 <= Wl - 1) ? 1.f : 0.f;
            float vx1 = (x0 >= -1 && x0 <= Wl - 2) ? 1.f : 0.f;
            float vy0 = (y0 >= 0 && y0 <= Wl - 1) ? 1.f : 0.f;
            float vy1 = (y0 >= -1 && y0 <= Wl - 2) ? 1.f : 0.f;
            float w00 = (1.f - fx) * (1.f - fy) * wgt * vx0 * vy0;
            float w01 = fx * (1.f - fy) * wgt * vx1 * vy0;
            float w10 = (1.f - fx) * fy * wgt * vx0 * vy1;
            float w11 = fx * fy * wgt * vx1 * vy1;
            int x0c = min(max(x0, 0), Wl - 1), x1c = min(max(x0 + 1, 0), Wl - 1);
            int y0c = min(max(y0, 0), Wl - 1), y1c = min(max(y0 + 1, 0), Wl - 1);
            int rb0 = s0 + y0c * Wl, rb1 = s0 + y1c * Wl;
            acc += w00 * bf4(vb + (size_t)(rb0 + x0c) * 256);
            acc += w01 * bf4(vb + (size_t)(rb0 + x1c) * 256);
            acc += w10 * bf4(vb + (size_t)(rb1 + x0c) * 256);
            acc += w11 * bf4(vb + (size_t)(rb1 + x1c) * 256);
        }
    }
#pragma unroll
    for (int l = 0; l < NLV; l++) {
#pragma unroll
        for (int v = 0; v < NVT; v++) {
            acc += WAs[qs][h * 48 + l * 12 + 4 + v] * bf4(vb + (size_t)(LSP + l * NVT + v) * 256);
        }
    }
    ushort4 ob;
    ob.x = f2bf(acc.x); ob.y = f2bf(acc.y); ob.z = f2bf(acc.z); ob.w = f2bf(acc.w);
    *(ushort4*)(attn + (size_t)bq * 256 + h * 32 + c4) = ob;
}

// ---------------- VT transformer layers (small) ----------------

__device__ __forceinline__ void blockReduce2_256(float& a, float& b, float* red, int tid)
{
#pragma unroll
    for (int off = 32; off > 0; off >>= 1) {
        a += __shfl_down(a, off, 64);
        b += __shfl_down(b, off, 64);
    }
    __syncthreads();
    int wid = tid >> 6;
    if ((tid & 63) == 0) { red[wid] = a; red[wid + 4] = b; }
    __syncthreads();
    a = red[0] + red[1] + red[2] + red[3];
    b = red[4] + red[5] + red[6] + red[7];
}

__device__ __forceinline__ float fetch_vts(const float* __restrict__ xtail, const float* __restrict__ seen,
                                           int b, int l, int t, int c)
{
    return (t < NVT) ? xtail[((size_t)b * 32 + l * NVT + t) * D_ + c]
                     : seen[(((size_t)b * NLV + l) * NSEEN + (t - NVT)) * D_ + c];
}

__global__ __launch_bounds__(256) void vt_qkv_k(const float* __restrict__ xtail, const float* __restrict__ seen,
                                                const float* __restrict__ wqkv, const float* __restrict__ bqkv,
                                                float* __restrict__ qkv)
{
    const int rt = blockIdx.x, cb = blockIdx.y, z = blockIdx.z;
    const int b = z >> 2, l = z & 3;
    __shared__ float As[ROWS][D_];
    const int tid = threadIdx.x;
    for (int idx = tid; idx < ROWS * D_; idx += 256) {
        int r = idx >> 8, c = idx & 255;
        int t = rt * ROWS + r;
        As[r][c] = (t < TVT) ? fetch_vts(xtail, seen, b, l, t, c) : 0.f;
    }
    __syncthreads();
    const float* W = wqkv + (size_t)l * D_ * 768;
    const int j = cb * 256 + tid;
    float acc[ROWS];
#pragma unroll
    for (int r = 0; r < ROWS; r++) acc[r] = 0.f;
    for (int i = 0; i < D_; i += 4) {
        float w0 = W[(size_t)(i + 0) * 768 + j];
        float w1 = W[(size_t)(i + 1) * 768 + j];
        float w2 = W[(size_t)(i + 2) * 768 + j];
        float w3 = W[(size_t)(i + 3) * 768 + j];
#pragma unroll
        for (int r = 0; r < ROWS; r++) {
            float4 a = *(const float4*)(&As[r][i]);
            acc[r] = fmaf(a.x, w0, acc[r]);
            acc[r] = fmaf(a.y, w1, acc[r]);
            acc[r] = fmaf(a.z, w2, acc[r]);
            acc[r] = fmaf(a.w, w3, acc[r]);
        }
    }
    float bj = bqkv[l * 768 + j];
#pragma unroll
    for (int r = 0; r < ROWS; r++) {
        int t = rt * ROWS + r;
        if (t < TVT) qkv[((size_t)z * TVT + t) * 768 + j] = acc[r] + bj;
    }
}

__global__ __launch_bounds__(128) void vt_attn_k(const float* __restrict__ qkv, float* __restrict__ o)
{
    const int z = blockIdx.x;
    const int h = z & 7, bl = z >> 3;
    __shared__ float Qs[TVT][33];
    __shared__ float Ks[TVT][DHD];
    __shared__ float Vs[TVT][DHD];
    __shared__ float Ss[TVT][73];
    const int tid = threadIdx.x;
    for (int idx = tid; idx < TVT * DHD; idx += 128) {
        int t = idx >> 5, d = idx & 31;
        const float* base = qkv + ((size_t)bl * TVT + t) * 768 + h * DHD + d;
        Qs[t][d] = base[0];
        Ks[t][d] = base[256];
        Vs[t][d] = base[512];
    }
    __syncthreads();
    if (tid < TVT) {
        const float scale = 0.17677669529663687f;
        float qr[DHD];
#pragma unroll
        for (int d = 0; d < DHD; d++) qr[d] = Qs[tid][d];
        float m = -1e30f;
        for (int k = 0; k < TVT; k++) {
            float s = 0.f;
#pragma unroll
            for (int d = 0; d < DHD; d++) s = fmaf(qr[d], Ks[k][d], s);
            s *= scale;
            Ss[tid][k] = s;
            m = fmaxf(m, s);
        }
        float sum = 0.f;
        for (int k = 0; k < TVT; k++) {
            float e = __expf(Ss[tid][k] - m);
            Ss[tid][k] = e;
            sum += e;
        }
        float inv = 1.f / sum;
        for (int d = 0; d < DHD; d++) {
            float acc = 0.f;
            for (int k = 0; k < TVT; k++) acc = fmaf(Ss[tid][k], Vs[k][d], acc);
            o[((size_t)bl * TVT + tid) * D_ + h * DHD + d] = acc * inv;
        }
    }
}

__global__ __launch_bounds__(256) void vt_proj_ln3_k(const float* __restrict__ obuf, const float* __restrict__ wproj,
                                                     const float* __restrict__ bproj, const float* __restrict__ xtail,
                                                     const float* __restrict__ seen, const float* __restrict__ g3,
                                                     const float* __restrict__ b3, float* __restrict__ vts2)
{
    const int rt = blockIdx.x, z = blockIdx.z;
    const int b = z >> 2, l = z & 3;
    __shared__ float As[ROWS][D_];
    __shared__ float Ts[ROWS][D_];
    __shared__ float red[8];
    const int tid = threadIdx.x;
    for (int idx = tid; idx < ROWS * D_; idx += 256) {
        int r = idx >> 8, c = idx & 255;
        int t = rt * ROWS + r;
        As[r][c] = (t < TVT) ? obuf[((size_t)z * TVT + t) * D_ + c] : 0.f;
    }
    __syncthreads();
    const float* W = wproj + (size_t)l * D_ * D_;
    const int j = tid;
    float acc[ROWS];
#pragma unroll
    for (int r = 0; r < ROWS; r++) acc[r] = 0.f;
    for (int i = 0; i < D_; i += 4) {
        float w0 = W[(size_t)(i + 0) * D_ + j];
        float w1 = W[(size_t)(i + 1) * D_ + j];
        float w2 = W[(size_t)(i + 2) * D_ + j];
        float w3 = W[(size_t)(i + 3) * D_ + j];
#pragma unroll
        for (int r = 0; r < ROWS; r++) {
            float4 a = *(const float4*)(&As[r][i]);
            acc[r] = fmaf(a.x, w0, acc[r]);
            acc[r] = fmaf(a.y, w1, acc[r]);
            acc[r] = fmaf(a.z, w2, acc[r]);
            acc[r] = fmaf(a.w, w3, acc[r]);
        }
    }
    float bj = bproj[l * D_ + j];
#pragma unroll
    for (int r = 0; r < ROWS; r++) {
        int t = rt * ROWS + r;
        if (t < TVT) Ts[r][j] = acc[r] + bj + fetch_vts(xtail, seen, b, l, t, j);
    }
    __syncthreads();
    float gj = g3[l * D_ + j], bej = b3[l * D_ + j];
    for (int r = 0; r < ROWS; r++) {
        int t = rt * ROWS + r;
        if (t >= TVT) continue;
        float v = Ts[r][j];
        float a = v, sq = v * v;
        blockReduce2_256(a, sq, red, tid);
        float mean = a * (1.f / D_);
        float var = sq * (1.f / D_) - mean * mean;
        vts2[((size_t)z * TVT + t) * D_ + j] = (v - mean) * rsqrtf(var + 1e-5f) * gj + bej;
    }
}

__global__ __launch_bounds__(256) void vt_mlp_ln4_k(const float* __restrict__ vts2, const float* __restrict__ wfc1,
                                                    const float* __restrict__ bfc1, const float* __restrict__ wfc2,
                                                    const float* __restrict__ bfc2, const float* __restrict__ g4,
                                                    const float* __restrict__ b4, float* __restrict__ out_seen,
                                                    float* __restrict__ out_sel)
{
    const int rt = blockIdx.x, z = blockIdx.z;
    const int b = z >> 2, l = z & 3;
    __shared__ float Xs[ROWS][D_];
    __shared__ float Hs[ROWS][FF];
    __shared__ float red[8];
    const int tid = threadIdx.x;
    for (int idx = tid; idx < ROWS * D_; idx += 256) {
        int r = idx >> 8, c = idx & 255;
        int t = rt * ROWS + r;
        Xs[r][c] = (t < TVT) ? vts2[((size_t)z * TVT + t) * D_ + c] : 0.f;
    }
    __syncthreads();
    const float* W1 = wfc1 + (size_t)l * D_ * FF;
    const float* W2 = wfc2 + (size_t)l * FF * D_;
    for (int cch = 0; cch < 4; cch++) {
        int j1 = cch * 256 + tid;
        float acc[ROWS];
#pragma unroll
        for (int r = 0; r < ROWS; r++) acc[r] = 0.f;
        for (int i = 0; i < D_; i += 4) {
            float w0 = W1[(size_t)(i + 0) * FF + j1];
            float w1 = W1[(size_t)(i + 1) * FF + j1];
            float w2 = W1[(size_t)(i + 2) * FF + j1];
            float w3 = W1[(size_t)(i + 3) * FF + j1];
#pragma unroll
            for (int r = 0; r < ROWS; r++) {
                float4 a = *(const float4*)(&Xs[r][i]);
                acc[r] = fmaf(a.x, w0, acc[r]);
                acc[r] = fmaf(a.y, w1, acc[r]);
                acc[r] = fmaf(a.z, w2, acc[r]);
                acc[r] = fmaf(a.w, w3, acc[r]);
            }
        }
        float bb = bfc1[l * FF + j1];
#pragma unroll
        for (int r = 0; r < ROWS; r++) {
            float v = acc[r] + bb;
            Hs[r][j1] = v * 0.5f * (1.f + erff(v * 0.70710678118654752f));
        }
    }
    __syncthreads();
    float acc2[ROWS];
#pragma unroll
    for (int r = 0; r < ROWS; r++) acc2[r] = 0.f;
    for (int i = 0; i < FF; i += 4) {
        float w0 = W2[(size_t)(i + 0) * D_ + tid];
        float w1 = W2[(size_t)(i + 1) * D_ + tid];
        float w2 = W2[(size_t)(i + 2) * D_ + tid];
        float w3 = W2[(size_t)(i + 3) * D_ + tid];
#pragma unroll
        for (int r = 0; r < ROWS; r++) {
            float4 hh = *(const float4*)(&Hs[r][i]);
            acc2[r] = fmaf(hh.x, w0, acc2[r]);
            acc2[r] = fmaf(hh.y, w1, acc2[r]);
            acc2[r] = fmaf(hh.z, w2, acc2[r]);
            acc2[r] = fmaf(hh.w, w3, acc2[r]);
        }
    }
    float bj = bfc2[l * D_ + tid], gj = g4[l * D_ + tid], bej = b4[l * D_ + tid];
    __syncthreads();
#pragma unroll
    for (int r = 0; r < ROWS; r++) Hs[r][tid] = acc2[r] + bj + Xs[r][tid];
    __syncthreads();
    for (int r = 0; r < ROWS; r++) {
        int t = rt * ROWS + r;
        if (t >= TVT) continue;
        float v = Hs[r][tid];
        float a = v, sq = v * v;
        blockReduce2_256(a, sq, red, tid);
        float mean = a * (1.f / D_);
        float var = sq * (1.f / D_) - mean * mean;
        float ov = (v - mean) * rsqrtf(var + 1e-5f) * gj + bej;
        if (t < NVT) out_sel[((size_t)b * 32 + l * NVT + t) * D_ + tid] = ov;
        else         out_seen[(((size_t)b * NLV + l) * NSEEN + (t - NVT)) * D_ + tid] = ov;
    }
}

// ---------------- launch ----------------

extern "C" void kernel_launch(void* const* d_in, const int* in_sizes, int n_in,
                              void* d_out, int out_size, void* d_ws, size_t ws_size,
                              hipStream_t stream)
{
    const float* src      = (const float*)d_in[0];
    const float* pos      = (const float*)d_in[1];
    const float* refp     = (const float*)d_in[2];
    const float* seen     = (const float*)d_in[5];
    const float* sel      = (const float*)d_in[6];
    const float* w_off    = (const float*)d_in[7];
    const float* b_off    = (const float*)d_in[8];
    const float* w_attn   = (const float*)d_in[9];
    const float* b_attn   = (const float*)d_in[10];
    const float* w_val    = (const float*)d_in[11];
    const float* b_val    = (const float*)d_in[12];
    const float* w_out    = (const float*)d_in[13];
    const float* b_out    = (const float*)d_in[14];
    const float* g1       = (const float*)d_in[15];
    const float* be1      = (const float*)d_in[16];
    const float* w_ff1    = (const float*)d_in[17];
    const float* b_ff1    = (const float*)d_in[18];
    const float* w_ff2    = (const float*)d_in[19];
    const float* b_ff2    = (const float*)d_in[20];
    const float* g2       = (const float*)d_in[21];
    const float* be2      = (const float*)d_in[22];
    const float* vt_wqkv  = (const float*)d_in[23];
    const float* vt_bqkv  = (const float*)d_in[24];
    const float* vt_wproj = (const float*)d_in[25];
    const float* vt_bproj = (const float*)d_in[26];
    const float* vt_g3    = (const float*)d_in[27];
    const float* vt_b3    = (const float*)d_in[28];
    const float* vt_g4    = (const float*)d_in[29];
    const float* vt_b4    = (const float*)d_in[30];
    const float* vt_wfc1  = (const float*)d_in[31];
    const float* vt_bfc1  = (const float*)d_in[32];
    const float* vt_wfc2  = (const float*)d_in[33];
    const float* vt_bfc2  = (const float*)d_in[34];

    float* ws = (float*)d_ws;
    // region map (f32 word offsets); lifetimes overlap deliberately:
    unsigned short* valueb = (unsigned short*)ws;    // 11157504 bf16 over [0, 5578752) f32 words
    float* offb  = ws + 11157504;                    // [11157504, 22315008)
    float* wall  = ws + 22315008;                    // [22315008, 39051264)
    unsigned short* a0b  = (unsigned short*)(ws + 39051264);
    unsigned short* a1b  = (unsigned short*)(ws + 44630016);
    unsigned short* attn = (unsigned short*)(ws + 39051264);   // over a0b (dead)
    unsigned short* xb   = (unsigned short*)(ws + 44630016);   // over a1b (dead)
    unsigned short* hb   = (unsigned short*)(ws + 11157504);   // over offb+wall (dead)
    float* y     = ws;                               // over valueb (dead after sample)
    float* y2    = ws;
    float* qkv   = ws;                               // VT phase
    float* obuf  = ws + 442368;
    float* vts2  = ws + 589824;
    float* xtail = ws + 50208768;                    // 16384
    unsigned short* wtb = (unsigned short*)(ws + 50225152);
    unsigned short* wvalT  = wtb;                    // 256x256
    unsigned short* woffT  = wtb + 65536;            // 256x256
    unsigned short* wattnT = wtb + 131072;           // 384x256
    unsigned short* woutT  = wtb + 229376;           // 256x256
    unsigned short* wff1T  = wtb + 294912;           // 1024x256
    unsigned short* wff2T  = wtb + 557056;           // 256x1024

    float* outx     = (float*)d_out;
    float* out_seen = outx + (size_t)BB * LSP * D_;
    float* out_sel  = out_seen + (size_t)BB * NLV * NSEEN * D_;

    // 1. weight converts
    cvt_wT_k<<<dim3(8, 8),  256, 0, stream>>>(w_val,  wvalT,  256, 256);
    cvt_wT_k<<<dim3(8, 8),  256, 0, stream>>>(w_off,  woffT,  256, 256);
    cvt_wT_k<<<dim3(12, 8), 256, 0, stream>>>(w_attn, wattnT, 256, 384);
    cvt_wT_k<<<dim3(8, 8),  256, 0, stream>>>(w_out,  woutT,  256, 256);
    cvt_wT_k<<<dim3(32, 8), 256, 0, stream>>>(w_ff1,  wff1T,  256, 1024);
    cvt_wT_k<<<dim3(8, 32), 256, 0, stream>>>(w_ff2,  wff2T,  1024, 256);
    // 2. input converts
    cvt_in_k<<<10896, 256, 0, stream>>>(src, pos, sel, a0b, a1b);
    // 3. projection GEMMs
    mfma_gemm_k<2><<<dim3(681, 4),  256, 0, stream>>>(a0b, wvalT,  b_val,  nullptr, valueb, 256, 256);
    mfma_gemm_k<0><<<dim3(681, 4),  256, 0, stream>>>(a1b, woffT,  b_off,  offb,  nullptr, 256, 256);
    mfma_gemm_k<0><<<dim3(681, 6),  256, 0, stream>>>(a1b, wattnT, b_attn, wall,  nullptr, 256, 384);
    softmax48_k<<<NBQ, 384, 0, stream>>>(wall);
    // 4. sampling (one wave per query)
    sample_k<<<NBQ / 4, 256, 0, stream>>>(valueb, offb, wall, refp, attn);
    // 5. out-proj + LN1 (LN1 also emits bf16 xb -> kills cvt_x pass)
    mfma_gemm_k<0><<<dim3(681, 4),  256, 0, stream>>>(attn, woutT, b_out, y, nullptr, 256, 256);
    resid_ln_k<<<NBQ / 4, 256, 0, stream>>>(y, src, sel, g1, be1, outx, xtail, xb);
    // 6. FFN + LN2
    mfma_gemm_k<1><<<dim3(681, 16), 256, 0, stream>>>(xb, wff1T, b_ff1, nullptr, hb, 256, 1024);
    mfma_gemm_k<0><<<dim3(681, 4),  256, 0, stream>>>(hb, wff2T, b_ff2, y2, nullptr, 1024, 256);
    resid_ln_k<<<NBQ / 4, 256, 0, stream>>>(y2, outx, xtail, g2, be2, outx, xtail, nullptr);
    // 7. VT chain
    vt_qkv_k<<<dim3(5, 3, 8), 256, 0, stream>>>(xtail, seen, vt_wqkv, vt_bqkv, qkv);
    vt_attn_k<<<BB * NLV * NH, 128, 0, stream>>>(qkv, obuf);
    vt_proj_ln3_k<<<dim3(5, 1, 8), 256, 0, stream>>>(obuf, vt_wproj, vt_bproj, xtail, seen, vt_g3, vt_b3, vts2);
    vt_mlp_ln4_k<<<dim3(5, 1, 8), 256, 0, stream>>>(vts2, vt_wfc1, vt_bfc1, vt_wfc2, vt_bfc2, vt_g4, vt_b4, out_seen, out_sel);
}

// Round 4
// 716.355 us; speedup vs baseline: 4.5407x; 1.3823x over previous
//
#include <hip/hip_runtime.h>
#include <math.h>

#define D_    256
#define NH    8
#define DHD   32
#define NLV   4
#define NPT   4
#define NVT   8
#define NSEEN 64
#define TVT   72
#define FF    1024
#define BB    2
#define LSP   21760
#define LQ    21792
#define NBQ   (BB*LQ)      // 43584
#define NVROW (8*TVT)      // 576 vt rows total

typedef __attribute__((ext_vector_type(8))) short short8;
typedef __attribute__((ext_vector_type(4))) float f32x4;

__device__ __forceinline__ unsigned short f2bf(float f)
{
    unsigned int u = __float_as_uint(f);
    u += 0x7fffu + ((u >> 16) & 1u);
    return (unsigned short)(u >> 16);
}

__device__ __forceinline__ f32x4 bf4(const unsigned short* p)
{
    ushort4 u = *(const ushort4*)p;
    f32x4 r;
    r.x = __uint_as_float((unsigned)u.x << 16);
    r.y = __uint_as_float((unsigned)u.y << 16);
    r.z = __uint_as_float((unsigned)u.z << 16);
    r.w = __uint_as_float((unsigned)u.w << 16);
    return r;
}

// ---------------- weight transpose+convert: Wt[z][n][k] = bf16(W[z][k][n]) ----------------
__global__ __launch_bounds__(256) void cvt_wT_k(const float* __restrict__ W, unsigned short* __restrict__ Wt,
                                                int K, int N)
{
    __shared__ float T[32][33];
    const int tid = threadIdx.x;
    const int z = blockIdx.z;
    const float* Wz = W + (size_t)z * K * N;
    unsigned short* Wtz = Wt + (size_t)z * N * K;
    const int n0 = blockIdx.x * 32, k0 = blockIdx.y * 32;
    const int tx = tid & 31, ty = tid >> 5;   // ty 0..7
#pragma unroll
    for (int s = 0; s < 4; s++)
        T[ty + 8 * s][tx] = Wz[(size_t)(k0 + ty + 8 * s) * N + n0 + tx];
    __syncthreads();
#pragma unroll
    for (int s = 0; s < 4; s++)
        Wtz[(size_t)(n0 + ty + 8 * s) * K + k0 + tx] = f2bf(T[tx][ty + 8 * s]);
}

// ---------------- input concat+convert ----------------
__global__ __launch_bounds__(256) void cvt_in_k(const float* __restrict__ src, const float* __restrict__ pos,
                                                const float* __restrict__ sel, unsigned short* __restrict__ a0,
                                                unsigned short* __restrict__ a1)
{
    size_t idx = ((size_t)blockIdx.x * 256 + threadIdx.x) * 4;
    int row = (int)(idx >> 8), c = (int)(idx & 255);
    int b = row / LQ, i = row - b * LQ;
    f32x4 v0, v1;
    if (i < LSP) {
        size_t g = ((size_t)b * LSP + i) * 256 + c;
        v0 = *(const f32x4*)(src + g);
        f32x4 p = *(const f32x4*)(pos + g);
        v1 = v0 + p;
    } else {
        size_t g = ((size_t)b * 32 + (i - LSP)) * 256 + c;
        v0 = *(const f32x4*)(sel + g);
        v1 = v0;
    }
    uint2 r0, r1;
    r0.x = (unsigned)f2bf(v0.x) | ((unsigned)f2bf(v0.y) << 16);
    r0.y = (unsigned)f2bf(v0.z) | ((unsigned)f2bf(v0.w) << 16);
    r1.x = (unsigned)f2bf(v1.x) | ((unsigned)f2bf(v1.y) << 16);
    r1.y = (unsigned)f2bf(v1.z) | ((unsigned)f2bf(v1.w) << 16);
    *(uint2*)(a0 + idx) = r0;
    *(uint2*)(a1 + idx) = r1;
}

// ---------------- MFMA GEMM: C[M][N] = A[M][K](bf16) @ B[N][K](bf16)^T + bias ----------------
// 64x64 tile, 4 waves, each wave 32x32 as 2x2 16x16x32 frags.
template<int MODE>   // 0: Cf f32   1: Cb bf16(relu)   2: Cb bf16
__global__ __launch_bounds__(256) void mfma_gemm_k(const unsigned short* __restrict__ A,
                                                   const unsigned short* __restrict__ B,
                                                   const float* __restrict__ bias,
                                                   float* __restrict__ Cf, unsigned short* __restrict__ Cb,
                                                   int K, int N)
{
    __shared__ __align__(16) short As[2048];   // [fr4][kg4][r16][8]
    __shared__ __align__(16) short Bs[2048];
    const int tid = threadIdx.x;
    const int row0 = blockIdx.x * 64;
    const int n0 = blockIdx.y * 64;
    const int w = tid >> 6, lane = tid & 63;
    const int r16 = lane & 15, q = lane >> 4;

    const unsigned short* gap = A + (size_t)(row0 + w * 16 + r16) * K + q * 8;
    const unsigned short* gbp = B + (size_t)(n0 + w * 16 + r16) * K + q * 8;
    short* sa = As + ((w * 4 + q) * 16 + r16) * 8;
    short* sb = Bs + ((w * 4 + q) * 16 + r16) * 8;

    const int wr2 = (w >> 1) * 2;
    const int wc2 = (w & 1) * 2;

    f32x4 acc[2][2] = {};
    for (int k0 = 0; k0 < K; k0 += 32) {
        *(short8*)sa = *(const short8*)(gap + k0);
        *(short8*)sb = *(const short8*)(gbp + k0);
        __syncthreads();
        short8 af0 = *(const short8*)(As + (((wr2 + 0) * 4 + q) * 16 + r16) * 8);
        short8 af1 = *(const short8*)(As + (((wr2 + 1) * 4 + q) * 16 + r16) * 8);
        short8 bf0 = *(const short8*)(Bs + (((wc2 + 0) * 4 + q) * 16 + r16) * 8);
        short8 bf1 = *(const short8*)(Bs + (((wc2 + 1) * 4 + q) * 16 + r16) * 8);
        acc[0][0] = __builtin_amdgcn_mfma_f32_16x16x32_bf16(af0, bf0, acc[0][0], 0, 0, 0);
        acc[0][1] = __builtin_amdgcn_mfma_f32_16x16x32_bf16(af0, bf1, acc[0][1], 0, 0, 0);
        acc[1][0] = __builtin_amdgcn_mfma_f32_16x16x32_bf16(af1, bf0, acc[1][0], 0, 0, 0);
        acc[1][1] = __builtin_amdgcn_mfma_f32_16x16x32_bf16(af1, bf1, acc[1][1], 0, 0, 0);
        __syncthreads();
    }
#pragma unroll
    for (int fm = 0; fm < 2; fm++) {
#pragma unroll
        for (int fn = 0; fn < 2; fn++) {
            int col = n0 + (w & 1) * 32 + fn * 16 + r16;
            float bj = bias[col];
#pragma unroll
            for (int i = 0; i < 4; i++) {
                int row = row0 + (w >> 1) * 32 + fm * 16 + q * 4 + i;
                float v = acc[fm][fn][i] + bj;
                if (MODE == 0)      Cf[(size_t)row * N + col] = v;
                else if (MODE == 1) Cb[(size_t)row * N + col] = f2bf(fmaxf(v, 0.f));
                else                Cb[(size_t)row * N + col] = f2bf(v);
            }
        }
    }
}

// ---------------- batched MFMA GEMM over z=(b,l): per-level weights, M rows/z ----------------
// A[z][M][K] bf16, B[l][N][K] bf16, bias[l][N], C[z][M][N]
template<int MODE>   // 0: Cf f32   3: Cb bf16(gelu)
__global__ __launch_bounds__(256) void mfma_bgemm_k(const unsigned short* __restrict__ A,
                                                    const unsigned short* __restrict__ B,
                                                    const float* __restrict__ bias,
                                                    float* __restrict__ Cf, unsigned short* __restrict__ Cb,
                                                    int M, int K, int N)
{
    __shared__ __align__(16) short As[2048];
    __shared__ __align__(16) short Bs[2048];
    const int tid = threadIdx.x;
    const int z = blockIdx.z, l = z & 3;
    const int row0 = blockIdx.x * 64;
    const int n0 = blockIdx.y * 64;
    const int w = tid >> 6, lane = tid & 63;
    const int r16 = lane & 15, q = lane >> 4;

    const int arow = min(row0 + w * 16 + r16, M - 1);
    const unsigned short* gap = A + (size_t)z * M * K + (size_t)arow * K + q * 8;
    const unsigned short* gbp = B + (size_t)l * N * K + (size_t)(n0 + w * 16 + r16) * K + q * 8;
    short* sa = As + ((w * 4 + q) * 16 + r16) * 8;
    short* sb = Bs + ((w * 4 + q) * 16 + r16) * 8;

    const int wr2 = (w >> 1) * 2;
    const int wc2 = (w & 1) * 2;

    f32x4 acc[2][2] = {};
    for (int k0 = 0; k0 < K; k0 += 32) {
        *(short8*)sa = *(const short8*)(gap + k0);
        *(short8*)sb = *(const short8*)(gbp + k0);
        __syncthreads();
        short8 af0 = *(const short8*)(As + (((wr2 + 0) * 4 + q) * 16 + r16) * 8);
        short8 af1 = *(const short8*)(As + (((wr2 + 1) * 4 + q) * 16 + r16) * 8);
        short8 bf0 = *(const short8*)(Bs + (((wc2 + 0) * 4 + q) * 16 + r16) * 8);
        short8 bf1 = *(const short8*)(Bs + (((wc2 + 1) * 4 + q) * 16 + r16) * 8);
        acc[0][0] = __builtin_amdgcn_mfma_f32_16x16x32_bf16(af0, bf0, acc[0][0], 0, 0, 0);
        acc[0][1] = __builtin_amdgcn_mfma_f32_16x16x32_bf16(af0, bf1, acc[0][1], 0, 0, 0);
        acc[1][0] = __builtin_amdgcn_mfma_f32_16x16x32_bf16(af1, bf0, acc[1][0], 0, 0, 0);
        acc[1][1] = __builtin_amdgcn_mfma_f32_16x16x32_bf16(af1, bf1, acc[1][1], 0, 0, 0);
        __syncthreads();
    }
#pragma unroll
    for (int fm = 0; fm < 2; fm++) {
#pragma unroll
        for (int fn = 0; fn < 2; fn++) {
            int col = n0 + (w & 1) * 32 + fn * 16 + r16;
            float bj = bias[l * N + col];
#pragma unroll
            for (int i = 0; i < 4; i++) {
                int row = row0 + (w >> 1) * 32 + fm * 16 + q * 4 + i;
                if (row >= M) continue;
                float v = acc[fm][fn][i] + bj;
                if (MODE == 0) Cf[(size_t)z * M * N + (size_t)row * N + col] = v;
                else {
                    float gl = v * 0.5f * (1.f + erff(v * 0.70710678118654752f));
                    Cb[(size_t)z * M * N + (size_t)row * N + col] = f2bf(gl);
                }
            }
        }
    }
}

// ---------------- softmax over groups of 48, in place on wall [NBQ][384] ----------------
__global__ __launch_bounds__(384) void softmax48_k(float* __restrict__ wall)
{
    __shared__ float Ls[384];
    __shared__ float Es[384];
    const int row = blockIdx.x, j = threadIdx.x;
    float v = wall[(size_t)row * 384 + j];
    Ls[j] = v;
    __syncthreads();
    const int g0 = (j / 48) * 48;
    float m = -1e30f;
    for (int k = 0; k < 48; k++) m = fmaxf(m, Ls[g0 + k]);
    float e = __expf(v - m);
    Es[j] = e;
    __syncthreads();
    float s = 0.f;
    for (int k = 0; k < 48; k++) s += Es[g0 + k];
    wall[(size_t)row * 384 + j] = e / s;
}

// ---------------- residual + LayerNorm: dst = LN(y + resid); optional bf16 copy ----------------
__global__ __launch_bounds__(256) void resid_ln_k(const float* __restrict__ y, const float* __restrict__ rsp,
                                                  const float* __restrict__ rtail, const float* __restrict__ g,
                                                  const float* __restrict__ be, float* __restrict__ dsp,
                                                  float* __restrict__ dtail, unsigned short* __restrict__ dbf)
{
    const int row = blockIdx.x * 4 + (threadIdx.x >> 6);
    const int lane = threadIdx.x & 63;
    const int b = row / LQ, i = row - b * LQ;
    f32x4 yv = *(const f32x4*)(y + (size_t)row * 256 + lane * 4);
    f32x4 rv;
    size_t didx;
    float* dbase;
    if (i < LSP) { size_t gidx = ((size_t)b * LSP + i) * 256; rv = *(const f32x4*)(rsp + gidx + lane * 4); dbase = dsp; didx = gidx; }
    else         { size_t gidx = ((size_t)b * 32 + (i - LSP)) * 256; rv = *(const f32x4*)(rtail + gidx + lane * 4); dbase = dtail; didx = gidx; }
    float t0 = yv.x + rv.x, t1 = yv.y + rv.y, t2 = yv.z + rv.z, t3 = yv.w + rv.w;
    float s = t0 + t1 + t2 + t3;
    float ss = t0 * t0 + t1 * t1 + t2 * t2 + t3 * t3;
#pragma unroll
    for (int off = 32; off; off >>= 1) {
        s += __shfl_xor(s, off, 64);
        ss += __shfl_xor(ss, off, 64);
    }
    float mean = s * (1.f / 256.f);
    float var = ss * (1.f / 256.f) - mean * mean;
    float rstd = rsqrtf(var + 1e-5f);
    int c = lane * 4;
    f32x4 gv = *(const f32x4*)(g + c);
    f32x4 bv = *(const f32x4*)(be + c);
    f32x4 o;
    o.x = (t0 - mean) * rstd * gv.x + bv.x;
    o.y = (t1 - mean) * rstd * gv.y + bv.y;
    o.z = (t2 - mean) * rstd * gv.z + bv.z;
    o.w = (t3 - mean) * rstd * gv.w + bv.w;
    *(f32x4*)(dbase + didx + c) = o;
    if (dbf) {
        ushort4 ob;
        ob.x = f2bf(o.x); ob.y = f2bf(o.y); ob.z = f2bf(o.z); ob.w = f2bf(o.w);
        *(ushort4*)(dbf + (size_t)row * 256 + c) = ob;
    }
}

// ---------------- deformable sampling + vt mix: one WAVE per query, bf16 value ----------------
__global__ __launch_bounds__(256) void sample_k(const unsigned short* __restrict__ value,
                                                const float* __restrict__ offb,
                                                const float* __restrict__ wall,
                                                const float* __restrict__ refp,
                                                unsigned short* __restrict__ attn)
{
    __shared__ float OFs[4][256];
    __shared__ float WAs[4][384];
    __shared__ float RPs[4][8];
    const int bq0 = blockIdx.x * 4;
    const int tid = threadIdx.x;
    {
        const float* p = offb + (size_t)bq0 * 256;
        for (int idx = tid; idx < 1024; idx += 256) OFs[idx >> 8][idx & 255] = p[idx];
        const float* pw = wall + (size_t)bq0 * 384;
        for (int idx = tid; idx < 1536; idx += 256) WAs[idx / 384][idx % 384] = pw[idx];
        const float* pr = refp + (size_t)bq0 * 8;
        if (tid < 32) RPs[tid >> 3][tid & 7] = pr[tid];
    }
    __syncthreads();
    const int qs = tid >> 6;
    const int lane = tid & 63;
    const int h = lane >> 3;
    const int c4 = (lane & 7) * 4;
    const int bq = bq0 + qs;
    const int b = bq / LQ;
    const unsigned short* vb = value + ((size_t)b * LQ) * 256 + h * 32 + c4;

    f32x4 acc = {0.f, 0.f, 0.f, 0.f};
    const int HL[4] = {128, 64, 32, 16};
    const int S0[4] = {0, 16384, 20480, 21504};
#pragma unroll
    for (int l = 0; l < NLV; l++) {
        const int Wl = HL[l];
        const int s0 = S0[l];
        float rx = RPs[qs][l * 2 + 0] * (float)Wl - 0.5f;
        float ry = RPs[qs][l * 2 + 1] * (float)Wl - 0.5f;
#pragma unroll
        for (int p = 0; p < NPT; p++) {
            float x = rx + OFs[qs][h * 32 + l * 8 + p * 2 + 0];
            float y = ry + OFs[qs][h * 32 + l * 8 + p * 2 + 1];
            float wgt = WAs[qs][h * 48 + l * 12 + p];
            float x0f = floorf(x), y0f = floorf(y);
            int x0 = (int)x0f, y0 = (int)y0f;
            float fx = x - x0f, fy = y - y0f;
            float vx0 = (x0 >= 0 && x0 <= Wl - 1) ? 1.f : 0.f;
            float vx1 = (x0 >= -1 && x0 <= Wl - 2) ? 1.f : 0.f;
            float vy0 = (y0 >= 0 && y0 <= Wl - 1) ? 1.f : 0.f;
            float vy1 = (y0 >= -1 && y0 <= Wl - 2) ? 1.f : 0.f;
            float w00 = (1.f - fx) * (1.f - fy) * wgt * vx0 * vy0;
            float w01 = fx * (1.f - fy) * wgt * vx1 * vy0;
            float w10 = (1.f - fx) * fy * wgt * vx0 * vy1;
            float w11 = fx * fy * wgt * vx1 * vy1;
            int x0c = min(max(x0, 0), Wl - 1), x1c = min(max(x0 + 1, 0), Wl - 1);
            int y0c = min(max(y0, 0), Wl - 1), y1c = min(max(y0 + 1, 0), Wl - 1);
            int rb0 = s0 + y0c * Wl, rb1 = s0 + y1c * Wl;
            acc += w00 * bf4(vb + (size_t)(rb0 + x0c) * 256);
            acc += w01 * bf4(vb + (size_t)(rb0 + x1c) * 256);
            acc += w10 * bf4(vb + (size_t)(rb1 + x0c) * 256);
            acc += w11 * bf4(vb + (size_t)(rb1 + x1c) * 256);
        }
    }
#pragma unroll
    for (int l = 0; l < NLV; l++) {
#pragma unroll
        for (int v = 0; v < NVT; v++) {
            acc += WAs[qs][h * 48 + l * 12 + 4 + v] * bf4(vb + (size_t)(LSP + l * NVT + v) * 256);
        }
    }
    ushort4 ob;
    ob.x = f2bf(acc.x); ob.y = f2bf(acc.y); ob.z = f2bf(acc.z); ob.w = f2bf(acc.w);
    *(ushort4*)(attn + (size_t)bq * 256 + h * 32 + c4) = ob;
}

// ---------------- VT support kernels ----------------

// build vtsf (f32) + vtsb (bf16), rows = [z=(b*4+l)][t<72]
__global__ __launch_bounds__(256) void vt_prep_k(const float* __restrict__ xtail, const float* __restrict__ seen,
                                                 float* __restrict__ vtsf, unsigned short* __restrict__ vtsb)
{
    const int row = blockIdx.x * 4 + (threadIdx.x >> 6);
    const int lane = threadIdx.x & 63;
    const int z = row / TVT, t = row - z * TVT;
    const int b = z >> 2, l = z & 3;
    const int c = lane * 4;
    f32x4 v;
    if (t < NVT) v = *(const f32x4*)(xtail + ((size_t)b * 32 + l * NVT + t) * 256 + c);
    else         v = *(const f32x4*)(seen + (((size_t)b * NLV + l) * NSEEN + (t - NVT)) * 256 + c);
    *(f32x4*)(vtsf + (size_t)row * 256 + c) = v;
    ushort4 ob;
    ob.x = f2bf(v.x); ob.y = f2bf(v.y); ob.z = f2bf(v.z); ob.w = f2bf(v.w);
    *(ushort4*)(vtsb + (size_t)row * 256 + c) = ob;
}

// attention per (b,l,h): 64 blocks, 128 threads; bf16 output
__global__ __launch_bounds__(128) void vt_attn_k(const float* __restrict__ qkv, unsigned short* __restrict__ o)
{
    const int z = blockIdx.x;
    const int h = z & 7, bl = z >> 3;
    __shared__ float Qs[TVT][33];
    __shared__ float Ks[TVT][DHD];
    __shared__ float Vs[TVT][DHD];
    __shared__ float Ss[TVT][73];
    const int tid = threadIdx.x;
    for (int idx = tid; idx < TVT * DHD; idx += 128) {
        int t = idx >> 5, d = idx & 31;
        const float* base = qkv + ((size_t)bl * TVT + t) * 768 + h * DHD + d;
        Qs[t][d] = base[0];
        Ks[t][d] = base[256];
        Vs[t][d] = base[512];
    }
    __syncthreads();
    if (tid < TVT) {
        const float scale = 0.17677669529663687f;
        float qr[DHD];
#pragma unroll
        for (int d = 0; d < DHD; d++) qr[d] = Qs[tid][d];
        float m = -1e30f;
        for (int k = 0; k < TVT; k++) {
            float s = 0.f;
#pragma unroll
            for (int d = 0; d < DHD; d++) s = fmaf(qr[d], Ks[k][d], s);
            s *= scale;
            Ss[tid][k] = s;
            m = fmaxf(m, s);
        }
        float sum = 0.f;
        for (int k = 0; k < TVT; k++) {
            float e = __expf(Ss[tid][k] - m);
            Ss[tid][k] = e;
            sum += e;
        }
        float inv = 1.f / sum;
        for (int d = 0; d < DHD; d++) {
            float acc = 0.f;
            for (int k = 0; k < TVT; k++) acc = fmaf(Ss[tid][k], Vs[k][d], acc);
            o[((size_t)bl * TVT + tid) * D_ + h * DHD + d] = f2bf(acc * inv);
        }
    }
}

// LN over vt rows: t = LN(y + resid) with per-level g/b.
// ROUTE 0: write dstf (f32) + dstb (bf16). ROUTE 1: route to out_sel/out_seen.
template<int ROUTE>
__global__ __launch_bounds__(256) void vt_ln_k(const float* __restrict__ y, const float* __restrict__ resid,
                                               const float* __restrict__ g, const float* __restrict__ be,
                                               float* __restrict__ dstf, unsigned short* __restrict__ dstb,
                                               float* __restrict__ out_sel, float* __restrict__ out_seen)
{
    const int row = blockIdx.x * 4 + (threadIdx.x >> 6);
    const int lane = threadIdx.x & 63;
    const int z = row / TVT, t = row - z * TVT;
    const int b = z >> 2, l = z & 3;
    const int c = lane * 4;
    f32x4 yv = *(const f32x4*)(y + (size_t)row * 256 + c);
    f32x4 rv = *(const f32x4*)(resid + (size_t)row * 256 + c);
    float t0 = yv.x + rv.x, t1 = yv.y + rv.y, t2 = yv.z + rv.z, t3 = yv.w + rv.w;
    float s = t0 + t1 + t2 + t3;
    float ss = t0 * t0 + t1 * t1 + t2 * t2 + t3 * t3;
#pragma unroll
    for (int off = 32; off; off >>= 1) {
        s += __shfl_xor(s, off, 64);
        ss += __shfl_xor(ss, off, 64);
    }
    float mean = s * (1.f / 256.f);
    float var = ss * (1.f / 256.f) - mean * mean;
    float rstd = rsqrtf(var + 1e-5f);
    f32x4 gv = *(const f32x4*)(g + l * 256 + c);
    f32x4 bv = *(const f32x4*)(be + l * 256 + c);
    f32x4 o;
    o.x = (t0 - mean) * rstd * gv.x + bv.x;
    o.y = (t1 - mean) * rstd * gv.y + bv.y;
    o.z = (t2 - mean) * rstd * gv.z + bv.z;
    o.w = (t3 - mean) * rstd * gv.w + bv.w;
    if (ROUTE == 0) {
        *(f32x4*)(dstf + (size_t)row * 256 + c) = o;
        ushort4 ob;
        ob.x = f2bf(o.x); ob.y = f2bf(o.y); ob.z = f2bf(o.z); ob.w = f2bf(o.w);
        *(ushort4*)(dstb + (size_t)row * 256 + c) = ob;
    } else {
        if (t < NVT) *(f32x4*)(out_sel + ((size_t)b * 32 + l * NVT + t) * 256 + c) = o;
        else         *(f32x4*)(out_seen + (((size_t)b * NLV + l) * NSEEN + (t - NVT)) * 256 + c) = o;
    }
}

// ---------------- launch ----------------

extern "C" void kernel_launch(void* const* d_in, const int* in_sizes, int n_in,
                              void* d_out, int out_size, void* d_ws, size_t ws_size,
                              hipStream_t stream)
{
    const float* src      = (const float*)d_in[0];
    const float* pos      = (const float*)d_in[1];
    const float* refp     = (const float*)d_in[2];
    const float* seen     = (const float*)d_in[5];
    const float* sel      = (const float*)d_in[6];
    const float* w_off    = (const float*)d_in[7];
    const float* b_off    = (const float*)d_in[8];
    const float* w_attn   = (const float*)d_in[9];
    const float* b_attn   = (const float*)d_in[10];
    const float* w_val    = (const float*)d_in[11];
    const float* b_val    = (const float*)d_in[12];
    const float* w_out    = (const float*)d_in[13];
    const float* b_out    = (const float*)d_in[14];
    const float* g1       = (const float*)d_in[15];
    const float* be1      = (const float*)d_in[16];
    const float* w_ff1    = (const float*)d_in[17];
    const float* b_ff1    = (const float*)d_in[18];
    const float* w_ff2    = (const float*)d_in[19];
    const float* b_ff2    = (const float*)d_in[20];
    const float* g2       = (const float*)d_in[21];
    const float* be2      = (const float*)d_in[22];
    const float* vt_wqkv  = (const float*)d_in[23];
    const float* vt_bqkv  = (const float*)d_in[24];
    const float* vt_wproj = (const float*)d_in[25];
    const float* vt_bproj = (const float*)d_in[26];
    const float* vt_g3    = (const float*)d_in[27];
    const float* vt_b3    = (const float*)d_in[28];
    const float* vt_g4    = (const float*)d_in[29];
    const float* vt_b4    = (const float*)d_in[30];
    const float* vt_wfc1  = (const float*)d_in[31];
    const float* vt_bfc1  = (const float*)d_in[32];
    const float* vt_wfc2  = (const float*)d_in[33];
    const float* vt_bfc2  = (const float*)d_in[34];

    float* ws = (float*)d_ws;
    // ---- main phase regions ----
    unsigned short* valueb = (unsigned short*)ws;    // bf16 value, [0, 5578752) f32 words
    float* offb  = ws + 11157504;
    float* wall  = ws + 22315008;
    unsigned short* a0b  = (unsigned short*)(ws + 39051264);
    unsigned short* a1b  = (unsigned short*)(ws + 44630016);
    unsigned short* attn = (unsigned short*)(ws + 39051264);   // over a0b (dead)
    unsigned short* xb   = (unsigned short*)(ws + 44630016);   // over a1b (dead)
    unsigned short* hb   = (unsigned short*)(ws + 11157504);   // over offb+wall (dead)
    float* y     = ws;
    float* y2    = ws;
    float* xtail = ws + 50208768;                    // 16384 words
    unsigned short* wtb = (unsigned short*)(ws + 50225152);
    unsigned short* wvalT  = wtb;
    unsigned short* woffT  = wtb + 65536;
    unsigned short* wattnT = wtb + 131072;
    unsigned short* woutT  = wtb + 229376;
    unsigned short* wff1T  = wtb + 294912;
    unsigned short* wff2T  = wtb + 557056;
    // ---- VT phase regions (over region 0, dead after ffn) ----
    float* vtsf  = ws;                               // [0, 147456)
    float* vts2f = ws + 147456;                      // [147456, 294912)
    float* yy    = ws + 294912;                      // [294912, 442368) shared yvt/y2vt
    float* qkvf  = ws + 442368;                      // [442368, 884736)
    unsigned short* vtsb   = (unsigned short*)(ws + 884736);    // 147456 bf16
    unsigned short* vts2b  = (unsigned short*)(ws + 958464);
    unsigned short* obufb  = (unsigned short*)(ws + 1032192);
    unsigned short* hvtb   = (unsigned short*)(ws + 1105920);   // 589824 bf16
    unsigned short* wqkvT  = (unsigned short*)(ws + 1400832);   // 4x768x256
    unsigned short* wprojT = (unsigned short*)(ws + 1794048);   // 4x256x256
    unsigned short* wfc1T  = (unsigned short*)(ws + 1925120);   // 4x1024x256
    unsigned short* wfc2T  = (unsigned short*)(ws + 2449408);   // 4x256x1024

    float* outx     = (float*)d_out;
    float* out_seen = outx + (size_t)BB * LSP * D_;
    float* out_sel  = out_seen + (size_t)BB * NLV * NSEEN * D_;

    // 1. main weight converts
    cvt_wT_k<<<dim3(8, 8),  256, 0, stream>>>(w_val,  wvalT,  256, 256);
    cvt_wT_k<<<dim3(8, 8),  256, 0, stream>>>(w_off,  woffT,  256, 256);
    cvt_wT_k<<<dim3(12, 8), 256, 0, stream>>>(w_attn, wattnT, 256, 384);
    cvt_wT_k<<<dim3(8, 8),  256, 0, stream>>>(w_out,  woutT,  256, 256);
    cvt_wT_k<<<dim3(32, 8), 256, 0, stream>>>(w_ff1,  wff1T,  256, 1024);
    cvt_wT_k<<<dim3(8, 32), 256, 0, stream>>>(w_ff2,  wff2T,  1024, 256);
    // 2. input converts
    cvt_in_k<<<10896, 256, 0, stream>>>(src, pos, sel, a0b, a1b);
    // 3. projection GEMMs
    mfma_gemm_k<2><<<dim3(681, 4),  256, 0, stream>>>(a0b, wvalT,  b_val,  nullptr, valueb, 256, 256);
    mfma_gemm_k<0><<<dim3(681, 4),  256, 0, stream>>>(a1b, woffT,  b_off,  offb,  nullptr, 256, 256);
    mfma_gemm_k<0><<<dim3(681, 6),  256, 0, stream>>>(a1b, wattnT, b_attn, wall,  nullptr, 256, 384);
    softmax48_k<<<NBQ, 384, 0, stream>>>(wall);
    // 4. sampling
    sample_k<<<NBQ / 4, 256, 0, stream>>>(valueb, offb, wall, refp, attn);
    // 5. out-proj + LN1
    mfma_gemm_k<0><<<dim3(681, 4),  256, 0, stream>>>(attn, woutT, b_out, y, nullptr, 256, 256);
    resid_ln_k<<<NBQ / 4, 256, 0, stream>>>(y, src, sel, g1, be1, outx, xtail, xb);
    // 6. FFN + LN2
    mfma_gemm_k<1><<<dim3(681, 16), 256, 0, stream>>>(xb, wff1T, b_ff1, nullptr, hb, 256, 1024);
    mfma_gemm_k<0><<<dim3(681, 4),  256, 0, stream>>>(hb, wff2T, b_ff2, y2, nullptr, 1024, 256);
    resid_ln_k<<<NBQ / 4, 256, 0, stream>>>(y2, outx, xtail, g2, be2, outx, xtail, nullptr);
    // 7. VT weight converts (region 0 now dead) + token prep
    cvt_wT_k<<<dim3(24, 8, 4), 256, 0, stream>>>(vt_wqkv,  wqkvT,  256, 768);
    cvt_wT_k<<<dim3(8, 8, 4),  256, 0, stream>>>(vt_wproj, wprojT, 256, 256);
    cvt_wT_k<<<dim3(32, 8, 4), 256, 0, stream>>>(vt_wfc1,  wfc1T,  256, 1024);
    cvt_wT_k<<<dim3(8, 32, 4), 256, 0, stream>>>(vt_wfc2,  wfc2T,  1024, 256);
    vt_prep_k<<<NVROW / 4, 256, 0, stream>>>(xtail, seen, vtsf, vtsb);
    // 8. VT chain (batched MFMA)
    mfma_bgemm_k<0><<<dim3(2, 12, 8), 256, 0, stream>>>(vtsb, wqkvT, vt_bqkv, qkvf, nullptr, TVT, 256, 768);
    vt_attn_k<<<BB * NLV * NH, 128, 0, stream>>>(qkvf, obufb);
    mfma_bgemm_k<0><<<dim3(2, 4, 8),  256, 0, stream>>>(obufb, wprojT, vt_bproj, yy, nullptr, TVT, 256, 256);
    vt_ln_k<0><<<NVROW / 4, 256, 0, stream>>>(yy, vtsf, vt_g3, vt_b3, vts2f, vts2b, nullptr, nullptr);
    mfma_bgemm_k<3><<<dim3(2, 16, 8), 256, 0, stream>>>(vts2b, wfc1T, vt_bfc1, nullptr, hvtb, TVT, 256, 1024);
    mfma_bgemm_k<0><<<dim3(2, 4, 8),  256, 0, stream>>>(hvtb, wfc2T, vt_bfc2, yy, nullptr, TVT, 1024, 256);
    vt_ln_k<1><<<NVROW / 4, 256, 0, stream>>>(yy, vts2f, vt_g4, vt_b4, nullptr, nullptr, out_sel, out_seen);
}

// Round 5
// 658.963 us; speedup vs baseline: 4.9362x; 1.0871x over previous
//
#include <hip/hip_runtime.h>
#include <hip/hip_fp16.h>
#include <math.h>

#define D_    256
#define NH    8
#define DHD   32
#define NLV   4
#define NPT   4
#define NVT   8
#define NSEEN 64
#define TVT   72
#define FF    1024
#define BB    2
#define LSP   21760
#define LQ    21792
#define NBQ   (BB*LQ)      // 43584
#define NVROW (8*TVT)      // 576 vt rows total
#define MT128 341          // ceil(NBQ/128)

typedef __attribute__((ext_vector_type(8))) short short8;
typedef __attribute__((ext_vector_type(4))) float f32x4;

__device__ __forceinline__ unsigned short f2bf(float f)
{
    unsigned int u = __float_as_uint(f);
    u += 0x7fffu + ((u >> 16) & 1u);
    return (unsigned short)(u >> 16);
}

__device__ __forceinline__ __half2 u2h(unsigned int u) { return *(__half2*)&u; }

__device__ __forceinline__ void gll16(const unsigned short* g, short* l)
{
    __builtin_amdgcn_global_load_lds((const __attribute__((address_space(1))) unsigned int*)g,
                                     (__attribute__((address_space(3))) unsigned int*)l,
                                     16, 0, 0);
}

// ---------------- weight transpose+convert: Wt[z][n][k] = bf16(W[z][k][n]) ----------------
__global__ __launch_bounds__(256) void cvt_wT_k(const float* __restrict__ W, unsigned short* __restrict__ Wt,
                                                int K, int N)
{
    __shared__ float T[32][33];
    const int tid = threadIdx.x;
    const int z = blockIdx.z;
    const float* Wz = W + (size_t)z * K * N;
    unsigned short* Wtz = Wt + (size_t)z * N * K;
    const int n0 = blockIdx.x * 32, k0 = blockIdx.y * 32;
    const int tx = tid & 31, ty = tid >> 5;
#pragma unroll
    for (int s = 0; s < 4; s++)
        T[ty + 8 * s][tx] = Wz[(size_t)(k0 + ty + 8 * s) * N + n0 + tx];
    __syncthreads();
#pragma unroll
    for (int s = 0; s < 4; s++)
        Wtz[(size_t)(n0 + ty + 8 * s) * K + k0 + tx] = f2bf(T[tx][ty + 8 * s]);
}

// ---------------- input concat+convert ----------------
__global__ __launch_bounds__(256) void cvt_in_k(const float* __restrict__ src, const float* __restrict__ pos,
                                                const float* __restrict__ sel, unsigned short* __restrict__ a0,
                                                unsigned short* __restrict__ a1)
{
    size_t idx = ((size_t)blockIdx.x * 256 + threadIdx.x) * 4;
    int row = (int)(idx >> 8), c = (int)(idx & 255);
    int b = row / LQ, i = row - b * LQ;
    f32x4 v0, v1;
    if (i < LSP) {
        size_t g = ((size_t)b * LSP + i) * 256 + c;
        v0 = *(const f32x4*)(src + g);
        f32x4 p = *(const f32x4*)(pos + g);
        v1 = v0 + p;
    } else {
        size_t g = ((size_t)b * 32 + (i - LSP)) * 256 + c;
        v0 = *(const f32x4*)(sel + g);
        v1 = v0;
    }
    uint2 r0, r1;
    r0.x = (unsigned)f2bf(v0.x) | ((unsigned)f2bf(v0.y) << 16);
    r0.y = (unsigned)f2bf(v0.z) | ((unsigned)f2bf(v0.w) << 16);
    r1.x = (unsigned)f2bf(v1.x) | ((unsigned)f2bf(v1.y) << 16);
    r1.y = (unsigned)f2bf(v1.z) | ((unsigned)f2bf(v1.w) << 16);
    *(uint2*)(a0 + idx) = r0;
    *(uint2*)(a1 + idx) = r1;
}

// ---------------- 128x128-tile MFMA GEMM with global_load_lds staging ----------------
// C[M][N] = A[M][K](bf16) @ B[N][K](bf16)^T + bias. 4 waves, each 64x64 (4x4 16x16x32 frags).
template<int MODE>   // 0: Cf f32   1: Cb bf16(relu)   4: Cb fp16
__global__ __launch_bounds__(256) void mfma_gemm128_k(const unsigned short* __restrict__ A,
                                                      const unsigned short* __restrict__ B,
                                                      const float* __restrict__ bias,
                                                      float* __restrict__ Cf, unsigned short* __restrict__ Cb,
                                                      int M, int K, int N)
{
    __shared__ __align__(16) short As[4096];   // [fr8][q4][r16][8]
    __shared__ __align__(16) short Bs[4096];
    const int tid = threadIdx.x;
    const int row0 = blockIdx.x * 128;
    const int n0 = blockIdx.y * 128;
    const int w = tid >> 6, lane = tid & 63;
    const int r16 = lane & 15, q = lane >> 4;
    const int wm = w >> 1, wn = w & 1;

    int ar0 = min(row0 + w * 16 + r16, M - 1);
    int ar1 = min(row0 + (w + 4) * 16 + r16, M - 1);
    const unsigned short* gA0 = A + (size_t)ar0 * K + q * 8;
    const unsigned short* gA1 = A + (size_t)ar1 * K + q * 8;
    const unsigned short* gB0 = B + (size_t)(n0 + w * 16 + r16) * K + q * 8;
    const unsigned short* gB1 = B + (size_t)(n0 + (w + 4) * 16 + r16) * K + q * 8;
    short* sA0 = As + ((w * 4 + q) * 16 + r16) * 8;
    short* sA1 = As + (((w + 4) * 4 + q) * 16 + r16) * 8;
    short* sB0 = Bs + ((w * 4 + q) * 16 + r16) * 8;
    short* sB1 = Bs + (((w + 4) * 4 + q) * 16 + r16) * 8;

    f32x4 acc[4][4] = {};
    for (int k0 = 0; k0 < K; k0 += 32) {
        gll16(gA0 + k0, sA0);
        gll16(gA1 + k0, sA1);
        gll16(gB0 + k0, sB0);
        gll16(gB1 + k0, sB1);
        __syncthreads();
        short8 af[4], bf[4];
#pragma unroll
        for (int i = 0; i < 4; i++) af[i] = *(const short8*)(As + (((wm * 4 + i) * 4 + q) * 16 + r16) * 8);
#pragma unroll
        for (int j = 0; j < 4; j++) bf[j] = *(const short8*)(Bs + (((wn * 4 + j) * 4 + q) * 16 + r16) * 8);
#pragma unroll
        for (int i = 0; i < 4; i++)
#pragma unroll
            for (int j = 0; j < 4; j++)
                acc[i][j] = __builtin_amdgcn_mfma_f32_16x16x32_bf16(af[i], bf[j], acc[i][j], 0, 0, 0);
        __syncthreads();
    }
#pragma unroll
    for (int j = 0; j < 4; j++) {
        int col = n0 + wn * 64 + j * 16 + r16;
        float bj = bias[col];
#pragma unroll
        for (int i = 0; i < 4; i++) {
#pragma unroll
            for (int ii = 0; ii < 4; ii++) {
                int row = row0 + wm * 64 + i * 16 + q * 4 + ii;
                if (row >= M) continue;
                float v = acc[i][j][ii] + bj;
                if (MODE == 0)      Cf[(size_t)row * N + col] = v;
                else if (MODE == 1) Cb[(size_t)row * N + col] = f2bf(fmaxf(v, 0.f));
                else { __half hv = __float2half(v); Cb[(size_t)row * N + col] = *(unsigned short*)&hv; }
            }
        }
    }
}

// ---------------- batched MFMA GEMM over z=(b,l): per-level weights (VT chain) ----------------
template<int MODE>   // 0: Cf f32   3: Cb bf16(gelu)
__global__ __launch_bounds__(256) void mfma_bgemm_k(const unsigned short* __restrict__ A,
                                                    const unsigned short* __restrict__ B,
                                                    const float* __restrict__ bias,
                                                    float* __restrict__ Cf, unsigned short* __restrict__ Cb,
                                                    int M, int K, int N)
{
    __shared__ __align__(16) short As[2048];
    __shared__ __align__(16) short Bs[2048];
    const int tid = threadIdx.x;
    const int z = blockIdx.z, l = z & 3;
    const int row0 = blockIdx.x * 64;
    const int n0 = blockIdx.y * 64;
    const int w = tid >> 6, lane = tid & 63;
    const int r16 = lane & 15, q = lane >> 4;

    const int arow = min(row0 + w * 16 + r16, M - 1);
    const unsigned short* gap = A + (size_t)z * M * K + (size_t)arow * K + q * 8;
    const unsigned short* gbp = B + (size_t)l * N * K + (size_t)(n0 + w * 16 + r16) * K + q * 8;
    short* sa = As + ((w * 4 + q) * 16 + r16) * 8;
    short* sb = Bs + ((w * 4 + q) * 16 + r16) * 8;

    const int wr2 = (w >> 1) * 2;
    const int wc2 = (w & 1) * 2;

    f32x4 acc[2][2] = {};
    for (int k0 = 0; k0 < K; k0 += 32) {
        *(short8*)sa = *(const short8*)(gap + k0);
        *(short8*)sb = *(const short8*)(gbp + k0);
        __syncthreads();
        short8 af0 = *(const short8*)(As + (((wr2 + 0) * 4 + q) * 16 + r16) * 8);
        short8 af1 = *(const short8*)(As + (((wr2 + 1) * 4 + q) * 16 + r16) * 8);
        short8 bf0 = *(const short8*)(Bs + (((wc2 + 0) * 4 + q) * 16 + r16) * 8);
        short8 bf1 = *(const short8*)(Bs + (((wc2 + 1) * 4 + q) * 16 + r16) * 8);
        acc[0][0] = __builtin_amdgcn_mfma_f32_16x16x32_bf16(af0, bf0, acc[0][0], 0, 0, 0);
        acc[0][1] = __builtin_amdgcn_mfma_f32_16x16x32_bf16(af0, bf1, acc[0][1], 0, 0, 0);
        acc[1][0] = __builtin_amdgcn_mfma_f32_16x16x32_bf16(af1, bf0, acc[1][0], 0, 0, 0);
        acc[1][1] = __builtin_amdgcn_mfma_f32_16x16x32_bf16(af1, bf1, acc[1][1], 0, 0, 0);
        __syncthreads();
    }
#pragma unroll
    for (int fm = 0; fm < 2; fm++) {
#pragma unroll
        for (int fn = 0; fn < 2; fn++) {
            int col = n0 + (w & 1) * 32 + fn * 16 + r16;
            float bj = bias[l * N + col];
#pragma unroll
            for (int i = 0; i < 4; i++) {
                int row = row0 + (w >> 1) * 32 + fm * 16 + q * 4 + i;
                if (row >= M) continue;
                float v = acc[fm][fn][i] + bj;
                if (MODE == 0) Cf[(size_t)z * M * N + (size_t)row * N + col] = v;
                else {
                    float gl = v * 0.5f * (1.f + erff(v * 0.70710678118654752f));
                    Cb[(size_t)z * M * N + (size_t)row * N + col] = f2bf(gl);
                }
            }
        }
    }
}

// ---------------- softmax over groups of 48, in place on wall [NBQ][384] ----------------
__global__ __launch_bounds__(384) void softmax48_k(float* __restrict__ wall)
{
    __shared__ float Ls[384];
    __shared__ float Es[384];
    const int row = blockIdx.x, j = threadIdx.x;
    float v = wall[(size_t)row * 384 + j];
    Ls[j] = v;
    __syncthreads();
    const int g0 = (j / 48) * 48;
    float m = -1e30f;
    for (int k = 0; k < 48; k++) m = fmaxf(m, Ls[g0 + k]);
    float e = __expf(v - m);
    Es[j] = e;
    __syncthreads();
    float s = 0.f;
    for (int k = 0; k < 48; k++) s += Es[g0 + k];
    wall[(size_t)row * 384 + j] = e / s;
}

// ---------------- residual + LayerNorm ----------------
__global__ __launch_bounds__(256) void resid_ln_k(const float* __restrict__ y, const float* __restrict__ rsp,
                                                  const float* __restrict__ rtail, const float* __restrict__ g,
                                                  const float* __restrict__ be, float* __restrict__ dsp,
                                                  float* __restrict__ dtail, unsigned short* __restrict__ dbf)
{
    const int row = blockIdx.x * 4 + (threadIdx.x >> 6);
    const int lane = threadIdx.x & 63;
    const int b = row / LQ, i = row - b * LQ;
    f32x4 yv = *(const f32x4*)(y + (size_t)row * 256 + lane * 4);
    f32x4 rv;
    size_t didx;
    float* dbase;
    if (i < LSP) { size_t gidx = ((size_t)b * LSP + i) * 256; rv = *(const f32x4*)(rsp + gidx + lane * 4); dbase = dsp; didx = gidx; }
    else         { size_t gidx = ((size_t)b * 32 + (i - LSP)) * 256; rv = *(const f32x4*)(rtail + gidx + lane * 4); dbase = dtail; didx = gidx; }
    float t0 = yv.x + rv.x, t1 = yv.y + rv.y, t2 = yv.z + rv.z, t3 = yv.w + rv.w;
    float s = t0 + t1 + t2 + t3;
    float ss = t0 * t0 + t1 * t1 + t2 * t2 + t3 * t3;
#pragma unroll
    for (int off = 32; off; off >>= 1) {
        s += __shfl_xor(s, off, 64);
        ss += __shfl_xor(ss, off, 64);
    }
    float mean = s * (1.f / 256.f);
    float var = ss * (1.f / 256.f) - mean * mean;
    float rstd = rsqrtf(var + 1e-5f);
    int c = lane * 4;
    f32x4 gv = *(const f32x4*)(g + c);
    f32x4 bv = *(const f32x4*)(be + c);
    f32x4 o;
    o.x = (t0 - mean) * rstd * gv.x + bv.x;
    o.y = (t1 - mean) * rstd * gv.y + bv.y;
    o.z = (t2 - mean) * rstd * gv.z + bv.z;
    o.w = (t3 - mean) * rstd * gv.w + bv.w;
    *(f32x4*)(dbase + didx + c) = o;
    if (dbf) {
        ushort4 ob;
        ob.x = f2bf(o.x); ob.y = f2bf(o.y); ob.z = f2bf(o.z); ob.w = f2bf(o.w);
        *(ushort4*)(dbf + (size_t)row * 256 + c) = ob;
    }
}

// ---------------- deformable sampling: phase-split weights (LDS) + fp16 pk-fma gather ----------------
// block = 4 queries; phase1: 512 tasks precompute half2 weights + byte offsets; phase2: gather.
__global__ __launch_bounds__(256) void sample_k(const unsigned short* __restrict__ value,  // fp16
                                                const float* __restrict__ offb,
                                                const float* __restrict__ wall,
                                                const float* __restrict__ refp,
                                                unsigned short* __restrict__ attn)
{
    __shared__ unsigned int Tsk[4][4][4][8][8];  // [q][l][p][h][w00,w01,w10,w11,i00,i01,i10,i11]
    __shared__ unsigned int Wvt[4][8][33];       // vt-mix half2 weights (32 used, padded)
    const int bq0 = blockIdx.x * 4;
    const int tid = threadIdx.x;
    const int HLc[4] = {128, 64, 32, 16};
    const int S0c[4] = {0, 16384, 20480, 21504};
    // phase 1: 2 tasks per thread
#pragma unroll
    for (int s = 0; s < 2; s++) {
        int tt = tid + 256 * s;                  // [q][h][l][p]
        int q = tt >> 7, h = (tt >> 4) & 7, l = (tt >> 2) & 3, p = tt & 3;
        int bq = bq0 + q;
        int Wl = HLc[l], s0 = S0c[l];
        float x = refp[(size_t)bq * 8 + l * 2 + 0] * (float)Wl - 0.5f + offb[(size_t)bq * 256 + h * 32 + l * 8 + p * 2 + 0];
        float y = refp[(size_t)bq * 8 + l * 2 + 1] * (float)Wl - 0.5f + offb[(size_t)bq * 256 + h * 32 + l * 8 + p * 2 + 1];
        float wgt = wall[(size_t)bq * 384 + h * 48 + l * 12 + p];
        float x0f = floorf(x), y0f = floorf(y);
        int x0 = (int)x0f, y0 = (int)y0f;
        float fx = x - x0f, fy = y - y0f;
        float vx0 = (x0 >= 0 && x0 <= Wl - 1) ? 1.f : 0.f;
        float vx1 = (x0 >= -1 && x0 <= Wl - 2) ? 1.f : 0.f;
        float vy0 = (y0 >= 0 && y0 <= Wl - 1) ? 1.f : 0.f;
        float vy1 = (y0 >= -1 && y0 <= Wl - 2) ? 1.f : 0.f;
        float w00 = (1.f - fx) * (1.f - fy) * wgt * vx0 * vy0;
        float w01 = fx * (1.f - fy) * wgt * vx1 * vy0;
        float w10 = (1.f - fx) * fy * wgt * vx0 * vy1;
        float w11 = fx * fy * wgt * vx1 * vy1;
        int x0c = min(max(x0, 0), Wl - 1), x1c = min(max(x0 + 1, 0), Wl - 1);
        int y0c = min(max(y0, 0), Wl - 1), y1c = min(max(y0 + 1, 0), Wl - 1);
        int rb0 = (s0 + y0c * Wl) * 512, rb1 = (s0 + y1c * Wl) * 512;
        unsigned int* T = &Tsk[q][l][p][h][0];
        __half2 hw;
        hw = __float2half2_rn(w00); T[0] = *(unsigned int*)&hw;
        hw = __float2half2_rn(w01); T[1] = *(unsigned int*)&hw;
        hw = __float2half2_rn(w10); T[2] = *(unsigned int*)&hw;
        hw = __float2half2_rn(w11); T[3] = *(unsigned int*)&hw;
        T[4] = rb0 + x0c * 512;
        T[5] = rb0 + x1c * 512;
        T[6] = rb1 + x0c * 512;
        T[7] = rb1 + x1c * 512;
    }
    for (int idx = tid; idx < 1024; idx += 256) {
        int q = idx >> 8, r = idx & 255;
        int h = r >> 5, j = r & 31;
        int l = j >> 3, v = j & 7;
        float wv = wall[(size_t)(bq0 + q) * 384 + h * 48 + l * 12 + 4 + v];
        __half2 hh = __float2half2_rn(wv);
        Wvt[q][h][j] = *(unsigned int*)&hh;
    }
    __syncthreads();
    // phase 2
    const int qs = tid >> 6, lane = tid & 63;
    const int h = lane >> 3, c4 = (lane & 7) * 4;
    const int bq = bq0 + qs, b = bq / LQ;
    const char* vbase = (const char*)value + ((size_t)b * LQ * 256 + h * 32 + c4) * 2;
    __half2 a0 = __float2half2_rn(0.f), a1 = a0;
#pragma unroll
    for (int l = 0; l < NLV; l++) {
#pragma unroll
        for (int p = 0; p < NPT; p++) {
            const unsigned int* T = &Tsk[qs][l][p][h][0];
            uint4 wv = *(const uint4*)T;
            uint4 iv = *(const uint4*)(T + 4);
            uint2 d;
            d = *(const uint2*)(vbase + iv.x); a0 = __hfma2(u2h(wv.x), u2h(d.x), a0); a1 = __hfma2(u2h(wv.x), u2h(d.y), a1);
            d = *(const uint2*)(vbase + iv.y); a0 = __hfma2(u2h(wv.y), u2h(d.x), a0); a1 = __hfma2(u2h(wv.y), u2h(d.y), a1);
            d = *(const uint2*)(vbase + iv.z); a0 = __hfma2(u2h(wv.z), u2h(d.x), a0); a1 = __hfma2(u2h(wv.z), u2h(d.y), a1);
            d = *(const uint2*)(vbase + iv.w); a0 = __hfma2(u2h(wv.w), u2h(d.x), a0); a1 = __hfma2(u2h(wv.w), u2h(d.y), a1);
        }
    }
#pragma unroll
    for (int j = 0; j < 32; j++) {
        unsigned int wv = Wvt[qs][h][j];
        uint2 d = *(const uint2*)(vbase + (size_t)(LSP + j) * 512);
        a0 = __hfma2(u2h(wv), u2h(d.x), a0);
        a1 = __hfma2(u2h(wv), u2h(d.y), a1);
    }
    float2 f0 = __half22float2(a0), f1 = __half22float2(a1);
    ushort4 ob;
    ob.x = f2bf(f0.x); ob.y = f2bf(f0.y); ob.z = f2bf(f1.x); ob.w = f2bf(f1.y);
    *(ushort4*)(attn + (size_t)bq * 256 + h * 32 + c4) = ob;
}

// ---------------- VT support kernels ----------------

__global__ __launch_bounds__(256) void vt_prep_k(const float* __restrict__ xtail, const float* __restrict__ seen,
                                                 float* __restrict__ vtsf, unsigned short* __restrict__ vtsb)
{
    const int row = blockIdx.x * 4 + (threadIdx.x >> 6);
    const int lane = threadIdx.x & 63;
    const int z = row / TVT, t = row - z * TVT;
    const int b = z >> 2, l = z & 3;
    const int c = lane * 4;
    f32x4 v;
    if (t < NVT) v = *(const f32x4*)(xtail + ((size_t)b * 32 + l * NVT + t) * 256 + c);
    else         v = *(const f32x4*)(seen + (((size_t)b * NLV + l) * NSEEN + (t - NVT)) * 256 + c);
    *(f32x4*)(vtsf + (size_t)row * 256 + c) = v;
    ushort4 ob;
    ob.x = f2bf(v.x); ob.y = f2bf(v.y); ob.z = f2bf(v.z); ob.w = f2bf(v.w);
    *(ushort4*)(vtsb + (size_t)row * 256 + c) = ob;
}

__global__ __launch_bounds__(128) void vt_attn_k(const float* __restrict__ qkv, unsigned short* __restrict__ o)
{
    const int z = blockIdx.x;
    const int h = z & 7, bl = z >> 3;
    __shared__ float Qs[TVT][33];
    __shared__ float Ks[TVT][DHD];
    __shared__ float Vs[TVT][DHD];
    __shared__ float Ss[TVT][73];
    const int tid = threadIdx.x;
    for (int idx = tid; idx < TVT * DHD; idx += 128) {
        int t = idx >> 5, d = idx & 31;
        const float* base = qkv + ((size_t)bl * TVT + t) * 768 + h * DHD + d;
        Qs[t][d] = base[0];
        Ks[t][d] = base[256];
        Vs[t][d] = base[512];
    }
    __syncthreads();
    if (tid < TVT) {
        const float scale = 0.17677669529663687f;
        float qr[DHD];
#pragma unroll
        for (int d = 0; d < DHD; d++) qr[d] = Qs[tid][d];
        float m = -1e30f;
        for (int k = 0; k < TVT; k++) {
            float s = 0.f;
#pragma unroll
            for (int d = 0; d < DHD; d++) s = fmaf(qr[d], Ks[k][d], s);
            s *= scale;
            Ss[tid][k] = s;
            m = fmaxf(m, s);
        }
        float sum = 0.f;
        for (int k = 0; k < TVT; k++) {
            float e = __expf(Ss[tid][k] - m);
            Ss[tid][k] = e;
            sum += e;
        }
        float inv = 1.f / sum;
        for (int d = 0; d < DHD; d++) {
            float acc = 0.f;
            for (int k = 0; k < TVT; k++) acc = fmaf(Ss[tid][k], Vs[k][d], acc);
            o[((size_t)bl * TVT + tid) * D_ + h * DHD + d] = f2bf(acc * inv);
        }
    }
}

template<int ROUTE>
__global__ __launch_bounds__(256) void vt_ln_k(const float* __restrict__ y, const float* __restrict__ resid,
                                               const float* __restrict__ g, const float* __restrict__ be,
                                               float* __restrict__ dstf, unsigned short* __restrict__ dstb,
                                               float* __restrict__ out_sel, float* __restrict__ out_seen)
{
    const int row = blockIdx.x * 4 + (threadIdx.x >> 6);
    const int lane = threadIdx.x & 63;
    const int z = row / TVT, t = row - z * TVT;
    const int b = z >> 2, l = z & 3;
    const int c = lane * 4;
    f32x4 yv = *(const f32x4*)(y + (size_t)row * 256 + c);
    f32x4 rv = *(const f32x4*)(resid + (size_t)row * 256 + c);
    float t0 = yv.x + rv.x, t1 = yv.y + rv.y, t2 = yv.z + rv.z, t3 = yv.w + rv.w;
    float s = t0 + t1 + t2 + t3;
    float ss = t0 * t0 + t1 * t1 + t2 * t2 + t3 * t3;
#pragma unroll
    for (int off = 32; off; off >>= 1) {
        s += __shfl_xor(s, off, 64);
        ss += __shfl_xor(ss, off, 64);
    }
    float mean = s * (1.f / 256.f);
    float var = ss * (1.f / 256.f) - mean * mean;
    float rstd = rsqrtf(var + 1e-5f);
    f32x4 gv = *(const f32x4*)(g + l * 256 + c);
    f32x4 bv = *(const f32x4*)(be + l * 256 + c);
    f32x4 o;
    o.x = (t0 - mean) * rstd * gv.x + bv.x;
    o.y = (t1 - mean) * rstd * gv.y + bv.y;
    o.z = (t2 - mean) * rstd * gv.z + bv.z;
    o.w = (t3 - mean) * rstd * gv.w + bv.w;
    if (ROUTE == 0) {
        *(f32x4*)(dstf + (size_t)row * 256 + c) = o;
        ushort4 ob;
        ob.x = f2bf(o.x); ob.y = f2bf(o.y); ob.z = f2bf(o.z); ob.w = f2bf(o.w);
        *(ushort4*)(dstb + (size_t)row * 256 + c) = ob;
    } else {
        if (t < NVT) *(f32x4*)(out_sel + ((size_t)b * 32 + l * NVT + t) * 256 + c) = o;
        else         *(f32x4*)(out_seen + (((size_t)b * NLV + l) * NSEEN + (t - NVT)) * 256 + c) = o;
    }
}

// ---------------- launch ----------------

extern "C" void kernel_launch(void* const* d_in, const int* in_sizes, int n_in,
                              void* d_out, int out_size, void* d_ws, size_t ws_size,
                              hipStream_t stream)
{
    const float* src      = (const float*)d_in[0];
    const float* pos      = (const float*)d_in[1];
    const float* refp     = (const float*)d_in[2];
    const float* seen     = (const float*)d_in[5];
    const float* sel      = (const float*)d_in[6];
    const float* w_off    = (const float*)d_in[7];
    const float* b_off    = (const float*)d_in[8];
    const float* w_attn   = (const float*)d_in[9];
    const float* b_attn   = (const float*)d_in[10];
    const float* w_val    = (const float*)d_in[11];
    const float* b_val    = (const float*)d_in[12];
    const float* w_out    = (const float*)d_in[13];
    const float* b_out    = (const float*)d_in[14];
    const float* g1       = (const float*)d_in[15];
    const float* be1      = (const float*)d_in[16];
    const float* w_ff1    = (const float*)d_in[17];
    const float* b_ff1    = (const float*)d_in[18];
    const float* w_ff2    = (const float*)d_in[19];
    const float* b_ff2    = (const float*)d_in[20];
    const float* g2       = (const float*)d_in[21];
    const float* be2      = (const float*)d_in[22];
    const float* vt_wqkv  = (const float*)d_in[23];
    const float* vt_bqkv  = (const float*)d_in[24];
    const float* vt_wproj = (const float*)d_in[25];
    const float* vt_bproj = (const float*)d_in[26];
    const float* vt_g3    = (const float*)d_in[27];
    const float* vt_b3    = (const float*)d_in[28];
    const float* vt_g4    = (const float*)d_in[29];
    const float* vt_b4    = (const float*)d_in[30];
    const float* vt_wfc1  = (const float*)d_in[31];
    const float* vt_bfc1  = (const float*)d_in[32];
    const float* vt_wfc2  = (const float*)d_in[33];
    const float* vt_bfc2  = (const float*)d_in[34];

    float* ws = (float*)d_ws;
    unsigned short* valueh = (unsigned short*)ws;    // fp16 value
    float* offb  = ws + 11157504;
    float* wall  = ws + 22315008;
    unsigned short* a0b  = (unsigned short*)(ws + 39051264);
    unsigned short* a1b  = (unsigned short*)(ws + 44630016);
    unsigned short* attn = (unsigned short*)(ws + 39051264);
    unsigned short* xb   = (unsigned short*)(ws + 44630016);
    unsigned short* hb   = (unsigned short*)(ws + 11157504);
    float* y     = ws;
    float* y2    = ws;
    float* xtail = ws + 50208768;
    unsigned short* wtb = (unsigned short*)(ws + 50225152);
    unsigned short* wvalT  = wtb;
    unsigned short* woffT  = wtb + 65536;
    unsigned short* wattnT = wtb + 131072;
    unsigned short* woutT  = wtb + 229376;
    unsigned short* wff1T  = wtb + 294912;
    unsigned short* wff2T  = wtb + 557056;
    // VT phase regions (over region 0, dead after ffn)
    float* vtsf  = ws;
    float* vts2f = ws + 147456;
    float* yy    = ws + 294912;
    float* qkvf  = ws + 442368;
    unsigned short* vtsb   = (unsigned short*)(ws + 884736);
    unsigned short* vts2b  = (unsigned short*)(ws + 958464);
    unsigned short* obufb  = (unsigned short*)(ws + 1032192);
    unsigned short* hvtb   = (unsigned short*)(ws + 1105920);
    unsigned short* wqkvT  = (unsigned short*)(ws + 1400832);
    unsigned short* wprojT = (unsigned short*)(ws + 1794048);
    unsigned short* wfc1T  = (unsigned short*)(ws + 1925120);
    unsigned short* wfc2T  = (unsigned short*)(ws + 2449408);

    float* outx     = (float*)d_out;
    float* out_seen = outx + (size_t)BB * LSP * D_;
    float* out_sel  = out_seen + (size_t)BB * NLV * NSEEN * D_;

    // 1. main weight converts
    cvt_wT_k<<<dim3(8, 8),  256, 0, stream>>>(w_val,  wvalT,  256, 256);
    cvt_wT_k<<<dim3(8, 8),  256, 0, stream>>>(w_off,  woffT,  256, 256);
    cvt_wT_k<<<dim3(12, 8), 256, 0, stream>>>(w_attn, wattnT, 256, 384);
    cvt_wT_k<<<dim3(8, 8),  256, 0, stream>>>(w_out,  woutT,  256, 256);
    cvt_wT_k<<<dim3(32, 8), 256, 0, stream>>>(w_ff1,  wff1T,  256, 1024);
    cvt_wT_k<<<dim3(8, 32), 256, 0, stream>>>(w_ff2,  wff2T,  1024, 256);
    // 2. input converts
    cvt_in_k<<<10896, 256, 0, stream>>>(src, pos, sel, a0b, a1b);
    // 3. projection GEMMs (128x128 tiles, global_load_lds)
    mfma_gemm128_k<4><<<dim3(MT128, 2), 256, 0, stream>>>(a0b, wvalT,  b_val,  nullptr, valueh, NBQ, 256, 256);
    mfma_gemm128_k<0><<<dim3(MT128, 2), 256, 0, stream>>>(a1b, woffT,  b_off,  offb,  nullptr, NBQ, 256, 256);
    mfma_gemm128_k<0><<<dim3(MT128, 3), 256, 0, stream>>>(a1b, wattnT, b_attn, wall,  nullptr, NBQ, 256, 384);
    softmax48_k<<<NBQ, 384, 0, stream>>>(wall);
    // 4. sampling
    sample_k<<<NBQ / 4, 256, 0, stream>>>(valueh, offb, wall, refp, attn);
    // 5. out-proj + LN1
    mfma_gemm128_k<0><<<dim3(MT128, 2), 256, 0, stream>>>(attn, woutT, b_out, y, nullptr, NBQ, 256, 256);
    resid_ln_k<<<NBQ / 4, 256, 0, stream>>>(y, src, sel, g1, be1, outx, xtail, xb);
    // 6. FFN + LN2
    mfma_gemm128_k<1><<<dim3(MT128, 8), 256, 0, stream>>>(xb, wff1T, b_ff1, nullptr, hb, NBQ, 256, 1024);
    mfma_gemm128_k<0><<<dim3(MT128, 2), 256, 0, stream>>>(hb, wff2T, b_ff2, y2, nullptr, NBQ, 1024, 256);
    resid_ln_k<<<NBQ / 4, 256, 0, stream>>>(y2, outx, xtail, g2, be2, outx, xtail, nullptr);
    // 7. VT weight converts + token prep
    cvt_wT_k<<<dim3(24, 8, 4), 256, 0, stream>>>(vt_wqkv,  wqkvT,  256, 768);
    cvt_wT_k<<<dim3(8, 8, 4),  256, 0, stream>>>(vt_wproj, wprojT, 256, 256);
    cvt_wT_k<<<dim3(32, 8, 4), 256, 0, stream>>>(vt_wfc1,  wfc1T,  256, 1024);
    cvt_wT_k<<<dim3(8, 32, 4), 256, 0, stream>>>(vt_wfc2,  wfc2T,  1024, 256);
    vt_prep_k<<<NVROW / 4, 256, 0, stream>>>(xtail, seen, vtsf, vtsb);
    // 8. VT chain (batched MFMA)
    mfma_bgemm_k<0><<<dim3(2, 12, 8), 256, 0, stream>>>(vtsb, wqkvT, vt_bqkv, qkvf, nullptr, TVT, 256, 768);
    vt_attn_k<<<BB * NLV * NH, 128, 0, stream>>>(qkvf, obufb);
    mfma_bgemm_k<0><<<dim3(2, 4, 8),  256, 0, stream>>>(obufb, wprojT, vt_bproj, yy, nullptr, TVT, 256, 256);
    vt_ln_k<0><<<NVROW / 4, 256, 0, stream>>>(yy, vtsf, vt_g3, vt_b3, vts2f, vts2b, nullptr, nullptr);
    mfma_bgemm_k<3><<<dim3(2, 16, 8), 256, 0, stream>>>(vts2b, wfc1T, vt_bfc1, nullptr, hvtb, TVT, 256, 1024);
    mfma_bgemm_k<0><<<dim3(2, 4, 8),  256, 0, stream>>>(hvtb, wfc2T, vt_bfc2, yy, nullptr, TVT, 1024, 256);
    vt_ln_k<1><<<NVROW / 4, 256, 0, stream>>>(yy, vts2f, vt_g4, vt_b4, nullptr, nullptr, out_sel, out_seen);
}

// Round 6
// 634.028 us; speedup vs baseline: 5.1303x; 1.0393x over previous
//
#include <hip/hip_runtime.h>
#include <hip/hip_fp16.h>
#include <math.h>

#define D_    256
#define NH    8
#define DHD   32
#define NLV   4
#define NPT   4
#define NVT   8
#define NSEEN 64
#define TVT   72
#define FF    1024
#define BB    2
#define LSP   21760
#define LQ    21792
#define NBQ   (BB*LQ)      // 43584
#define NVROW (8*TVT)      // 576
#define MT128 341          // ceil(NBQ/128)

typedef __attribute__((ext_vector_type(8))) short short8;
typedef __attribute__((ext_vector_type(4))) float f32x4;

__device__ __forceinline__ unsigned short f2bf(float f)
{
    unsigned int u = __float_as_uint(f);
    u += 0x7fffu + ((u >> 16) & 1u);
    return (unsigned short)(u >> 16);
}
__device__ __forceinline__ float bf2f(unsigned short u) { return __uint_as_float((unsigned)u << 16); }
__device__ __forceinline__ __half2 u2h(unsigned int u) { return *(__half2*)&u; }
__device__ __forceinline__ unsigned int pack2(float a, float b)
{
    __half2 h = __halves2half2(__float2half_rn(a), __float2half_rn(b));
    return *(unsigned int*)&h;
}

__device__ __forceinline__ void gll16(const unsigned short* g, short* l)
{
    __builtin_amdgcn_global_load_lds((const __attribute__((address_space(1))) unsigned int*)g,
                                     (__attribute__((address_space(3))) unsigned int*)l,
                                     16, 0, 0);
}

// ---------------- weight transpose+convert: Wt[z][n][k] = bf16(W[z][k][n]) ----------------
__global__ __launch_bounds__(256) void cvt_wT_k(const float* __restrict__ W, unsigned short* __restrict__ Wt,
                                                int K, int N)
{
    __shared__ float T[32][33];
    const int tid = threadIdx.x;
    const int z = blockIdx.z;
    const float* Wz = W + (size_t)z * K * N;
    unsigned short* Wtz = Wt + (size_t)z * N * K;
    const int n0 = blockIdx.x * 32, k0 = blockIdx.y * 32;
    const int tx = tid & 31, ty = tid >> 5;
#pragma unroll
    for (int s = 0; s < 4; s++)
        T[ty + 8 * s][tx] = Wz[(size_t)(k0 + ty + 8 * s) * N + n0 + tx];
    __syncthreads();
#pragma unroll
    for (int s = 0; s < 4; s++)
        Wtz[(size_t)(n0 + ty + 8 * s) * K + k0 + tx] = f2bf(T[tx][ty + 8 * s]);
}

// ---------------- input concat+convert ----------------
__global__ __launch_bounds__(256) void cvt_in_k(const float* __restrict__ src, const float* __restrict__ pos,
                                                const float* __restrict__ sel, unsigned short* __restrict__ a0,
                                                unsigned short* __restrict__ a1)
{
    size_t idx = ((size_t)blockIdx.x * 256 + threadIdx.x) * 4;
    int row = (int)(idx >> 8), c = (int)(idx & 255);
    int b = row / LQ, i = row - b * LQ;
    f32x4 v0, v1;
    if (i < LSP) {
        size_t g = ((size_t)b * LSP + i) * 256 + c;
        v0 = *(const f32x4*)(src + g);
        f32x4 p = *(const f32x4*)(pos + g);
        v1 = v0 + p;
    } else {
        size_t g = ((size_t)b * 32 + (i - LSP)) * 256 + c;
        v0 = *(const f32x4*)(sel + g);
        v1 = v0;
    }
    uint2 r0, r1;
    r0.x = (unsigned)f2bf(v0.x) | ((unsigned)f2bf(v0.y) << 16);
    r0.y = (unsigned)f2bf(v0.z) | ((unsigned)f2bf(v0.w) << 16);
    r1.x = (unsigned)f2bf(v1.x) | ((unsigned)f2bf(v1.y) << 16);
    r1.y = (unsigned)f2bf(v1.z) | ((unsigned)f2bf(v1.w) << 16);
    *(uint2*)(a0 + idx) = r0;
    *(uint2*)(a1 + idx) = r1;
}

// ---------------- 128x128-tile MFMA GEMM, global_load_lds staging ----------------
// MODE 1: Cb = bf16(relu)   MODE 4: Cb = fp16   MODE 5: split col<256->Cb (bias), else Cb2 (bias2), bf16
template<int MODE>
__global__ __launch_bounds__(256) void mfma_gemm128_k(const unsigned short* __restrict__ A,
                                                      const unsigned short* __restrict__ B,
                                                      const float* __restrict__ bias,
                                                      const float* __restrict__ bias2,
                                                      unsigned short* __restrict__ Cb,
                                                      unsigned short* __restrict__ Cb2,
                                                      int M, int K, int N)
{
    __shared__ __align__(16) short As[4096];
    __shared__ __align__(16) short Bs[4096];
    const int tid = threadIdx.x;
    const int row0 = blockIdx.x * 128;
    const int n0 = blockIdx.y * 128;
    const int w = tid >> 6, lane = tid & 63;
    const int r16 = lane & 15, q = lane >> 4;
    const int wm = w >> 1, wn = w & 1;

    int ar0 = min(row0 + w * 16 + r16, M - 1);
    int ar1 = min(row0 + (w + 4) * 16 + r16, M - 1);
    const unsigned short* gA0 = A + (size_t)ar0 * K + q * 8;
    const unsigned short* gA1 = A + (size_t)ar1 * K + q * 8;
    const unsigned short* gB0 = B + (size_t)(n0 + w * 16 + r16) * K + q * 8;
    const unsigned short* gB1 = B + (size_t)(n0 + (w + 4) * 16 + r16) * K + q * 8;
    short* sA0 = As + ((w * 4 + q) * 16 + r16) * 8;
    short* sA1 = As + (((w + 4) * 4 + q) * 16 + r16) * 8;
    short* sB0 = Bs + ((w * 4 + q) * 16 + r16) * 8;
    short* sB1 = Bs + (((w + 4) * 4 + q) * 16 + r16) * 8;

    f32x4 acc[4][4] = {};
    for (int k0 = 0; k0 < K; k0 += 32) {
        gll16(gA0 + k0, sA0);
        gll16(gA1 + k0, sA1);
        gll16(gB0 + k0, sB0);
        gll16(gB1 + k0, sB1);
        __syncthreads();
        short8 af[4], bf[4];
#pragma unroll
        for (int i = 0; i < 4; i++) af[i] = *(const short8*)(As + (((wm * 4 + i) * 4 + q) * 16 + r16) * 8);
#pragma unroll
        for (int j = 0; j < 4; j++) bf[j] = *(const short8*)(Bs + (((wn * 4 + j) * 4 + q) * 16 + r16) * 8);
#pragma unroll
        for (int i = 0; i < 4; i++)
#pragma unroll
            for (int j = 0; j < 4; j++)
                acc[i][j] = __builtin_amdgcn_mfma_f32_16x16x32_bf16(af[i], bf[j], acc[i][j], 0, 0, 0);
        __syncthreads();
    }
#pragma unroll
    for (int j = 0; j < 4; j++) {
        int col = n0 + wn * 64 + j * 16 + r16;
        float bj = (MODE == 5) ? (col < 256 ? bias[col] : bias2[col - 256]) : bias[col];
#pragma unroll
        for (int i = 0; i < 4; i++) {
#pragma unroll
            for (int ii = 0; ii < 4; ii++) {
                int row = row0 + wm * 64 + i * 16 + q * 4 + ii;
                if (row >= M) continue;
                float v = acc[i][j][ii] + bj;
                if (MODE == 1)      Cb[(size_t)row * N + col] = f2bf(fmaxf(v, 0.f));
                else if (MODE == 4) { __half hv = __float2half(v); Cb[(size_t)row * N + col] = *(unsigned short*)&hv; }
                else {
                    if (col < 256) Cb[(size_t)row * 256 + col] = f2bf(v);
                    else           Cb2[(size_t)row * 384 + col - 256] = f2bf(v);
                }
            }
        }
    }
}

// ---------------- fused GEMM (N=256 full row) + bias + residual + LayerNorm ----------------
// tile 128 rows x 256 cols; wave w owns rows [w*32, w*32+32). RESID 0: resid=rsp/rtail, write dsp/dtail + xbf bf16.
// RESID 1: resid = dsp/dtail in place.
template<int RESID>
__global__ __launch_bounds__(256) void gemm_ln_k(const unsigned short* __restrict__ A,
                                                 const unsigned short* __restrict__ B,
                                                 const float* __restrict__ bias,
                                                 const float* __restrict__ g, const float* __restrict__ be,
                                                 const float* __restrict__ rsp, const float* __restrict__ rtail,
                                                 float* __restrict__ dsp, float* __restrict__ dtail,
                                                 unsigned short* __restrict__ xbf, int K)
{
    __shared__ __align__(16) short As[4096];   // 128x32
    __shared__ __align__(16) short Bs[8192];   // 256x32
    const int tid = threadIdx.x;
    const int row0 = blockIdx.x * 128;
    const int w = tid >> 6, lane = tid & 63;
    const int r16 = lane & 15, q = lane >> 4;

    const unsigned short* gA[2]; short* lA[2];
    const unsigned short* gB[4]; short* lB[4];
#pragma unroll
    for (int a = 0; a < 2; a++) {
        int idx8 = a * 256 + tid;
        int fr = idx8 >> 6, qq = (idx8 >> 4) & 3, rr = idx8 & 15;
        int row = min(row0 + fr * 16 + rr, NBQ - 1);
        gA[a] = A + (size_t)row * K + qq * 8;
        lA[a] = As + idx8 * 8;
    }
#pragma unroll
    for (int bp = 0; bp < 4; bp++) {
        int idx8 = bp * 256 + tid;
        int fr = idx8 >> 6, qq = (idx8 >> 4) & 3, rr = idx8 & 15;
        gB[bp] = B + (size_t)(fr * 16 + rr) * K + qq * 8;
        lB[bp] = Bs + idx8 * 8;
    }

    f32x4 acc[2][16] = {};
    for (int k0 = 0; k0 < K; k0 += 32) {
        gll16(gA[0] + k0, lA[0]);
        gll16(gA[1] + k0, lA[1]);
        gll16(gB[0] + k0, lB[0]);
        gll16(gB[1] + k0, lB[1]);
        gll16(gB[2] + k0, lB[2]);
        gll16(gB[3] + k0, lB[3]);
        __syncthreads();
        short8 af[2];
#pragma unroll
        for (int fm = 0; fm < 2; fm++) af[fm] = *(const short8*)(As + (((w * 2 + fm) * 4 + q) * 16 + r16) * 8);
#pragma unroll
        for (int fn = 0; fn < 16; fn++) {
            short8 bfr = *(const short8*)(Bs + ((fn * 4 + q) * 16 + r16) * 8);
            acc[0][fn] = __builtin_amdgcn_mfma_f32_16x16x32_bf16(af[0], bfr, acc[0][fn], 0, 0, 0);
            acc[1][fn] = __builtin_amdgcn_mfma_f32_16x16x32_bf16(af[1], bfr, acc[1][fn], 0, 0, 0);
        }
        __syncthreads();
    }
    // stage g/be/bias in LDS (reuse As)
    float* sG  = (float*)As;
    float* sBe = sG + 256;
    float* sBi = sBe + 256;
    sG[tid] = g[tid]; sBe[tid] = be[tid]; sBi[tid] = bias[tid];
    __syncthreads();

#pragma unroll
    for (int fm = 0; fm < 2; fm++) {
#pragma unroll
        for (int i = 0; i < 4; i++) {
            int row = row0 + w * 32 + fm * 16 + q * 4 + i;
            bool valid = row < NBQ;
            int bb = valid ? row / LQ : 0;
            int ir = row - bb * LQ;
            float tv[16];
            float s = 0.f, ss = 0.f;
#pragma unroll
            for (int fn = 0; fn < 16; fn++) {
                int col = fn * 16 + r16;
                float v = acc[fm][fn][i] + sBi[col];
                float rr = 0.f;
                if (valid) {
                    if (RESID == 0) rr = (ir < LSP) ? rsp[((size_t)bb * LSP + ir) * 256 + col]
                                                    : rtail[((size_t)bb * 32 + ir - LSP) * 256 + col];
                    else            rr = (ir < LSP) ? dsp[((size_t)bb * LSP + ir) * 256 + col]
                                                    : dtail[((size_t)bb * 32 + ir - LSP) * 256 + col];
                }
                float t = v + rr;
                tv[fn] = t; s += t; ss += t * t;
            }
#pragma unroll
            for (int m = 1; m < 16; m <<= 1) {
                s += __shfl_xor(s, m, 64);
                ss += __shfl_xor(ss, m, 64);
            }
            float mean = s * (1.f / 256.f);
            float var = ss * (1.f / 256.f) - mean * mean;
            float rstd = rsqrtf(var + 1e-5f);
            if (valid) {
#pragma unroll
                for (int fn = 0; fn < 16; fn++) {
                    int col = fn * 16 + r16;
                    float o = (tv[fn] - mean) * rstd * sG[col] + sBe[col];
                    if (ir < LSP) dsp[((size_t)bb * LSP + ir) * 256 + col] = o;
                    else          dtail[((size_t)bb * 32 + ir - LSP) * 256 + col] = o;
                    if (RESID == 0) xbf[(size_t)row * 256 + col] = f2bf(o);
                }
            }
        }
    }
}

// ---------------- batched MFMA GEMM over z=(b,l): per-level weights (VT chain) ----------------
template<int MODE>   // 0: Cf f32   3: Cb bf16(gelu)
__global__ __launch_bounds__(256) void mfma_bgemm_k(const unsigned short* __restrict__ A,
                                                    const unsigned short* __restrict__ B,
                                                    const float* __restrict__ bias,
                                                    float* __restrict__ Cf, unsigned short* __restrict__ Cb,
                                                    int M, int K, int N)
{
    __shared__ __align__(16) short As[2048];
    __shared__ __align__(16) short Bs[2048];
    const int tid = threadIdx.x;
    const int z = blockIdx.z, l = z & 3;
    const int row0 = blockIdx.x * 64;
    const int n0 = blockIdx.y * 64;
    const int w = tid >> 6, lane = tid & 63;
    const int r16 = lane & 15, q = lane >> 4;

    const int arow = min(row0 + w * 16 + r16, M - 1);
    const unsigned short* gap = A + (size_t)z * M * K + (size_t)arow * K + q * 8;
    const unsigned short* gbp = B + (size_t)l * N * K + (size_t)(n0 + w * 16 + r16) * K + q * 8;
    short* sa = As + ((w * 4 + q) * 16 + r16) * 8;
    short* sb = Bs + ((w * 4 + q) * 16 + r16) * 8;

    const int wr2 = (w >> 1) * 2;
    const int wc2 = (w & 1) * 2;

    f32x4 acc[2][2] = {};
    for (int k0 = 0; k0 < K; k0 += 32) {
        *(short8*)sa = *(const short8*)(gap + k0);
        *(short8*)sb = *(const short8*)(gbp + k0);
        __syncthreads();
        short8 af0 = *(const short8*)(As + (((wr2 + 0) * 4 + q) * 16 + r16) * 8);
        short8 af1 = *(const short8*)(As + (((wr2 + 1) * 4 + q) * 16 + r16) * 8);
        short8 bf0 = *(const short8*)(Bs + (((wc2 + 0) * 4 + q) * 16 + r16) * 8);
        short8 bf1 = *(const short8*)(Bs + (((wc2 + 1) * 4 + q) * 16 + r16) * 8);
        acc[0][0] = __builtin_amdgcn_mfma_f32_16x16x32_bf16(af0, bf0, acc[0][0], 0, 0, 0);
        acc[0][1] = __builtin_amdgcn_mfma_f32_16x16x32_bf16(af0, bf1, acc[0][1], 0, 0, 0);
        acc[1][0] = __builtin_amdgcn_mfma_f32_16x16x32_bf16(af1, bf0, acc[1][0], 0, 0, 0);
        acc[1][1] = __builtin_amdgcn_mfma_f32_16x16x32_bf16(af1, bf1, acc[1][1], 0, 0, 0);
        __syncthreads();
    }
#pragma unroll
    for (int fm = 0; fm < 2; fm++) {
#pragma unroll
        for (int fn = 0; fn < 2; fn++) {
            int col = n0 + (w & 1) * 32 + fn * 16 + r16;
            float bj = bias[l * N + col];
#pragma unroll
            for (int i = 0; i < 4; i++) {
                int row = row0 + (w >> 1) * 32 + fm * 16 + q * 4 + i;
                if (row >= M) continue;
                float v = acc[fm][fn][i] + bj;
                if (MODE == 0) Cf[(size_t)z * M * N + (size_t)row * N + col] = v;
                else {
                    float gl = v * 0.5f * (1.f + erff(v * 0.70710678118654752f));
                    Cb[(size_t)z * M * N + (size_t)row * N + col] = f2bf(gl);
                }
            }
        }
    }
}

// ---------------- deformable sampling: fused softmax + phase-split + fp16 pk-fma gather ----------------
__global__ __launch_bounds__(256) void sample_k(const unsigned short* __restrict__ value,  // fp16
                                                const unsigned short* __restrict__ offbb,  // bf16 [NBQ][256]
                                                const unsigned short* __restrict__ wallb,  // bf16 logits [NBQ][384]
                                                const float* __restrict__ refp,
                                                unsigned short* __restrict__ attn)
{
    __shared__ float SM[4][8][49];      // softmaxed weights (padded)
    __shared__ float OFs[4][8][33];     // offsets (padded)
    __shared__ float RPs[4][8];
    __shared__ uint2 Twt[4][4][4][8];   // packed half weights (w00,w01),(w10,w11)
    __shared__ uint4 Tix[4][4][4][8];   // byte offsets
    const int bq0 = blockIdx.x * 4;
    const int tid = threadIdx.x;
    // stage logits + offsets + refp
    for (int idx = tid; idx < 1536; idx += 256) {
        int qq = idx / 384, c = idx - qq * 384;
        SM[qq][c / 48][c % 48] = bf2f(wallb[(size_t)(bq0 + qq) * 384 + c]);
    }
    for (int idx = tid; idx < 1024; idx += 256) {
        int qq = idx >> 8, c = idx & 255;
        OFs[qq][c >> 5][c & 31] = bf2f(offbb[(size_t)(bq0 + qq) * 256 + c]);
    }
    if (tid < 32) RPs[tid >> 3][tid & 7] = refp[(size_t)bq0 * 8 + tid];
    __syncthreads();
    // softmax-48 per (q,h): 32 groups x 8 lanes x 6 elems
    {
        int j = tid & 7, gidx = tid >> 3;
        int qq = gidx >> 3, h = gidx & 7;
        float* row = &SM[qq][h][0];
        float v[6];
#pragma unroll
        for (int k = 0; k < 6; k++) v[k] = row[j * 6 + k];
        float m = v[0];
#pragma unroll
        for (int k = 1; k < 6; k++) m = fmaxf(m, v[k]);
        m = fmaxf(m, __shfl_xor(m, 1, 64));
        m = fmaxf(m, __shfl_xor(m, 2, 64));
        m = fmaxf(m, __shfl_xor(m, 4, 64));
        float s = 0.f;
#pragma unroll
        for (int k = 0; k < 6; k++) { v[k] = __expf(v[k] - m); s += v[k]; }
        s += __shfl_xor(s, 1, 64);
        s += __shfl_xor(s, 2, 64);
        s += __shfl_xor(s, 4, 64);
        float inv = 1.f / s;
#pragma unroll
        for (int k = 0; k < 6; k++) row[j * 6 + k] = v[k] * inv;
    }
    __syncthreads();
    // phase 1: 512 tasks [q][l][p][h]
    const int HLc[4] = {128, 64, 32, 16};
    const int S0c[4] = {0, 16384, 20480, 21504};
#pragma unroll
    for (int s = 0; s < 2; s++) {
        int tt = tid + 256 * s;
        int qq = tt >> 7, l = (tt >> 5) & 3, p = (tt >> 3) & 3, h = tt & 7;
        int Wl = HLc[l], s0 = S0c[l];
        float x = RPs[qq][l * 2 + 0] * (float)Wl - 0.5f + OFs[qq][h][l * 8 + p * 2 + 0];
        float y = RPs[qq][l * 2 + 1] * (float)Wl - 0.5f + OFs[qq][h][l * 8 + p * 2 + 1];
        float wgt = SM[qq][h][l * 12 + p];
        float x0f = floorf(x), y0f = floorf(y);
        int x0 = (int)x0f, y0 = (int)y0f;
        float fx = x - x0f, fy = y - y0f;
        float vx0 = (x0 >= 0 && x0 <= Wl - 1) ? 1.f : 0.f;
        float vx1 = (x0 >= -1 && x0 <= Wl - 2) ? 1.f : 0.f;
        float vy0 = (y0 >= 0 && y0 <= Wl - 1) ? 1.f : 0.f;
        float vy1 = (y0 >= -1 && y0 <= Wl - 2) ? 1.f : 0.f;
        float w00 = (1.f - fx) * (1.f - fy) * wgt * vx0 * vy0;
        float w01 = fx * (1.f - fy) * wgt * vx1 * vy0;
        float w10 = (1.f - fx) * fy * wgt * vx0 * vy1;
        float w11 = fx * fy * wgt * vx1 * vy1;
        int x0c = min(max(x0, 0), Wl - 1), x1c = min(max(x0 + 1, 0), Wl - 1);
        int y0c = min(max(y0, 0), Wl - 1), y1c = min(max(y0 + 1, 0), Wl - 1);
        int rb0 = (s0 + y0c * Wl) * 512, rb1 = (s0 + y1c * Wl) * 512;
        Twt[qq][l][p][h] = make_uint2(pack2(w00, w01), pack2(w10, w11));
        Tix[qq][l][p][h] = make_uint4(rb0 + x0c * 512, rb0 + x1c * 512, rb1 + x0c * 512, rb1 + x1c * 512);
    }
    __syncthreads();
    // phase 2: gather
    const int qs = tid >> 6, lane = tid & 63;
    const int h = lane >> 3, c4 = (lane & 7) * 4;
    const int bq = bq0 + qs, b = bq / LQ;
    const char* vbase = (const char*)value + ((size_t)b * LQ * 256 + h * 32 + c4) * 2;
    __half2 a0 = __float2half2_rn(0.f), a1 = a0;
#pragma unroll
    for (int l = 0; l < NLV; l++) {
#pragma unroll
        for (int p = 0; p < NPT; p++) {
            uint2 wp = *(const uint2*)&Twt[qs][l][p][h];
            uint4 iv = *(const uint4*)&Tix[qs][l][p][h];
            __half2 wx = u2h(wp.x), wy = u2h(wp.y);
            __half2 w00 = __low2half2(wx), w01 = __high2half2(wx);
            __half2 w10 = __low2half2(wy), w11 = __high2half2(wy);
            uint2 d;
            d = *(const uint2*)(vbase + iv.x); a0 = __hfma2(w00, u2h(d.x), a0); a1 = __hfma2(w00, u2h(d.y), a1);
            d = *(const uint2*)(vbase + iv.y); a0 = __hfma2(w01, u2h(d.x), a0); a1 = __hfma2(w01, u2h(d.y), a1);
            d = *(const uint2*)(vbase + iv.z); a0 = __hfma2(w10, u2h(d.x), a0); a1 = __hfma2(w10, u2h(d.y), a1);
            d = *(const uint2*)(vbase + iv.w); a0 = __hfma2(w11, u2h(d.x), a0); a1 = __hfma2(w11, u2h(d.y), a1);
        }
    }
#pragma unroll
    for (int j = 0; j < 32; j++) {
        int l = j >> 3, v = j & 7;
        __half2 wv = __float2half2_rn(SM[qs][h][l * 12 + 4 + v]);
        uint2 d = *(const uint2*)(vbase + (size_t)(LSP + j) * 512);
        a0 = __hfma2(wv, u2h(d.x), a0);
        a1 = __hfma2(wv, u2h(d.y), a1);
    }
    float2 f0 = __half22float2(a0), f1 = __half22float2(a1);
    ushort4 ob;
    ob.x = f2bf(f0.x); ob.y = f2bf(f0.y); ob.z = f2bf(f1.x); ob.w = f2bf(f1.y);
    *(ushort4*)(attn + (size_t)bq * 256 + h * 32 + c4) = ob;
}

// ---------------- VT support kernels ----------------

__global__ __launch_bounds__(256) void vt_prep_k(const float* __restrict__ xtail, const float* __restrict__ seen,
                                                 float* __restrict__ vtsf, unsigned short* __restrict__ vtsb)
{
    const int row = blockIdx.x * 4 + (threadIdx.x >> 6);
    const int lane = threadIdx.x & 63;
    const int z = row / TVT, t = row - z * TVT;
    const int b = z >> 2, l = z & 3;
    const int c = lane * 4;
    f32x4 v;
    if (t < NVT) v = *(const f32x4*)(xtail + ((size_t)b * 32 + l * NVT + t) * 256 + c);
    else         v = *(const f32x4*)(seen + (((size_t)b * NLV + l) * NSEEN + (t - NVT)) * 256 + c);
    *(f32x4*)(vtsf + (size_t)row * 256 + c) = v;
    ushort4 ob;
    ob.x = f2bf(v.x); ob.y = f2bf(v.y); ob.z = f2bf(v.z); ob.w = f2bf(v.w);
    *(ushort4*)(vtsb + (size_t)row * 256 + c) = ob;
}

__global__ __launch_bounds__(128) void vt_attn_k(const float* __restrict__ qkv, unsigned short* __restrict__ o)
{
    const int z = blockIdx.x;
    const int h = z & 7, bl = z >> 3;
    __shared__ float Qs[TVT][33];
    __shared__ float Ks[TVT][DHD];
    __shared__ float Vs[TVT][DHD];
    __shared__ float Ss[TVT][73];
    const int tid = threadIdx.x;
    for (int idx = tid; idx < TVT * DHD; idx += 128) {
        int t = idx >> 5, d = idx & 31;
        const float* base = qkv + ((size_t)bl * TVT + t) * 768 + h * DHD + d;
        Qs[t][d] = base[0];
        Ks[t][d] = base[256];
        Vs[t][d] = base[512];
    }
    __syncthreads();
    if (tid < TVT) {
        const float scale = 0.17677669529663687f;
        float qr[DHD];
#pragma unroll
        for (int d = 0; d < DHD; d++) qr[d] = Qs[tid][d];
        float m = -1e30f;
        for (int k = 0; k < TVT; k++) {
            float s = 0.f;
#pragma unroll
            for (int d = 0; d < DHD; d++) s = fmaf(qr[d], Ks[k][d], s);
            s *= scale;
            Ss[tid][k] = s;
            m = fmaxf(m, s);
        }
        float sum = 0.f;
        for (int k = 0; k < TVT; k++) {
            float e = __expf(Ss[tid][k] - m);
            Ss[tid][k] = e;
            sum += e;
        }
        float inv = 1.f / sum;
        for (int d = 0; d < DHD; d++) {
            float acc = 0.f;
            for (int k = 0; k < TVT; k++) acc = fmaf(Ss[tid][k], Vs[k][d], acc);
            o[((size_t)bl * TVT + tid) * D_ + h * DHD + d] = f2bf(acc * inv);
        }
    }
}

template<int ROUTE>
__global__ __launch_bounds__(256) void vt_ln_k(const float* __restrict__ y, const float* __restrict__ resid,
                                               const float* __restrict__ g, const float* __restrict__ be,
                                               float* __restrict__ dstf, unsigned short* __restrict__ dstb,
                                               float* __restrict__ out_sel, float* __restrict__ out_seen)
{
    const int row = blockIdx.x * 4 + (threadIdx.x >> 6);
    const int lane = threadIdx.x & 63;
    const int z = row / TVT, t = row - z * TVT;
    const int b = z >> 2, l = z & 3;
    const int c = lane * 4;
    f32x4 yv = *(const f32x4*)(y + (size_t)row * 256 + c);
    f32x4 rv = *(const f32x4*)(resid + (size_t)row * 256 + c);
    float t0 = yv.x + rv.x, t1 = yv.y + rv.y, t2 = yv.z + rv.z, t3 = yv.w + rv.w;
    float s = t0 + t1 + t2 + t3;
    float ss = t0 * t0 + t1 * t1 + t2 * t2 + t3 * t3;
#pragma unroll
    for (int off = 32; off; off >>= 1) {
        s += __shfl_xor(s, off, 64);
        ss += __shfl_xor(ss, off, 64);
    }
    float mean = s * (1.f / 256.f);
    float var = ss * (1.f / 256.f) - mean * mean;
    float rstd = rsqrtf(var + 1e-5f);
    f32x4 gv = *(const f32x4*)(g + l * 256 + c);
    f32x4 bv = *(const f32x4*)(be + l * 256 + c);
    f32x4 o;
    o.x = (t0 - mean) * rstd * gv.x + bv.x;
    o.y = (t1 - mean) * rstd * gv.y + bv.y;
    o.z = (t2 - mean) * rstd * gv.z + bv.z;
    o.w = (t3 - mean) * rstd * gv.w + bv.w;
    if (ROUTE == 0) {
        *(f32x4*)(dstf + (size_t)row * 256 + c) = o;
        ushort4 ob;
        ob.x = f2bf(o.x); ob.y = f2bf(o.y); ob.z = f2bf(o.z); ob.w = f2bf(o.w);
        *(ushort4*)(dstb + (size_t)row * 256 + c) = ob;
    } else {
        if (t < NVT) *(f32x4*)(out_sel + ((size_t)b * 32 + l * NVT + t) * 256 + c) = o;
        else         *(f32x4*)(out_seen + (((size_t)b * NLV + l) * NSEEN + (t - NVT)) * 256 + c) = o;
    }
}

// ---------------- launch ----------------

extern "C" void kernel_launch(void* const* d_in, const int* in_sizes, int n_in,
                              void* d_out, int out_size, void* d_ws, size_t ws_size,
                              hipStream_t stream)
{
    const float* src      = (const float*)d_in[0];
    const float* pos      = (const float*)d_in[1];
    const float* refp     = (const float*)d_in[2];
    const float* seen     = (const float*)d_in[5];
    const float* sel      = (const float*)d_in[6];
    const float* w_off    = (const float*)d_in[7];
    const float* b_off    = (const float*)d_in[8];
    const float* w_attn   = (const float*)d_in[9];
    const float* b_attn   = (const float*)d_in[10];
    const float* w_val    = (const float*)d_in[11];
    const float* b_val    = (const float*)d_in[12];
    const float* w_out    = (const float*)d_in[13];
    const float* b_out    = (const float*)d_in[14];
    const float* g1       = (const float*)d_in[15];
    const float* be1      = (const float*)d_in[16];
    const float* w_ff1    = (const float*)d_in[17];
    const float* b_ff1    = (const float*)d_in[18];
    const float* w_ff2    = (const float*)d_in[19];
    const float* b_ff2    = (const float*)d_in[20];
    const float* g2       = (const float*)d_in[21];
    const float* be2      = (const float*)d_in[22];
    const float* vt_wqkv  = (const float*)d_in[23];
    const float* vt_bqkv  = (const float*)d_in[24];
    const float* vt_wproj = (const float*)d_in[25];
    const float* vt_bproj = (const float*)d_in[26];
    const float* vt_g3    = (const float*)d_in[27];
    const float* vt_b3    = (const float*)d_in[28];
    const float* vt_g4    = (const float*)d_in[29];
    const float* vt_b4    = (const float*)d_in[30];
    const float* vt_wfc1  = (const float*)d_in[31];
    const float* vt_bfc1  = (const float*)d_in[32];
    const float* vt_wfc2  = (const float*)d_in[33];
    const float* vt_bfc2  = (const float*)d_in[34];

    float* ws = (float*)d_ws;
    unsigned short* valueh = (unsigned short*)ws;              // fp16 value [NBQ][256]
    unsigned short* offbb  = (unsigned short*)(ws + 11157504); // bf16 [NBQ][256]
    unsigned short* wallb  = (unsigned short*)(ws + 22315008); // bf16 [NBQ][384]
    unsigned short* a0b  = (unsigned short*)(ws + 39051264);
    unsigned short* a1b  = (unsigned short*)(ws + 44630016);
    unsigned short* attn = (unsigned short*)(ws + 39051264);   // over a0b (dead)
    unsigned short* xb   = (unsigned short*)(ws + 44630016);   // over a1b (dead)
    unsigned short* hb   = (unsigned short*)(ws + 11157504);   // over offbb+wallb (dead)
    float* xtail = ws + 50208768;
    unsigned short* wtb = (unsigned short*)(ws + 50225152);
    unsigned short* wvalT  = wtb;                  // 256x256
    unsigned short* wcatT  = wtb + 65536;          // 640x256 (off || attn)
    unsigned short* woutT  = wtb + 229376;         // 256x256
    unsigned short* wff1T  = wtb + 294912;         // 1024x256
    unsigned short* wff2T  = wtb + 557056;         // 256x1024
    // VT phase regions (over region 0, dead after ffn)
    float* vtsf  = ws;
    float* vts2f = ws + 147456;
    float* yy    = ws + 294912;
    float* qkvf  = ws + 442368;
    unsigned short* vtsb   = (unsigned short*)(ws + 884736);
    unsigned short* vts2b  = (unsigned short*)(ws + 958464);
    unsigned short* obufb  = (unsigned short*)(ws + 1032192);
    unsigned short* hvtb   = (unsigned short*)(ws + 1105920);
    unsigned short* wqkvT  = (unsigned short*)(ws + 1400832);
    unsigned short* wprojT = (unsigned short*)(ws + 1794048);
    unsigned short* wfc1T  = (unsigned short*)(ws + 1925120);
    unsigned short* wfc2T  = (unsigned short*)(ws + 2449408);

    float* outx     = (float*)d_out;
    float* out_seen = outx + (size_t)BB * LSP * D_;
    float* out_sel  = out_seen + (size_t)BB * NLV * NSEEN * D_;

    // 1. weight converts
    cvt_wT_k<<<dim3(8, 8),  256, 0, stream>>>(w_val,  wvalT,  256, 256);
    cvt_wT_k<<<dim3(8, 8),  256, 0, stream>>>(w_off,  wcatT,  256, 256);
    cvt_wT_k<<<dim3(12, 8), 256, 0, stream>>>(w_attn, wcatT + 65536, 256, 384);
    cvt_wT_k<<<dim3(8, 8),  256, 0, stream>>>(w_out,  woutT,  256, 256);
    cvt_wT_k<<<dim3(32, 8), 256, 0, stream>>>(w_ff1,  wff1T,  256, 1024);
    cvt_wT_k<<<dim3(8, 32), 256, 0, stream>>>(w_ff2,  wff2T,  1024, 256);
    // 2. input converts
    cvt_in_k<<<10896, 256, 0, stream>>>(src, pos, sel, a0b, a1b);
    // 3. projection GEMMs
    mfma_gemm128_k<4><<<dim3(MT128, 2), 256, 0, stream>>>(a0b, wvalT, b_val, nullptr, valueh, nullptr, NBQ, 256, 256);
    mfma_gemm128_k<5><<<dim3(MT128, 5), 256, 0, stream>>>(a1b, wcatT, b_off, b_attn, offbb, wallb, NBQ, 256, 640);
    // 4. sampling (softmax fused)
    sample_k<<<NBQ / 4, 256, 0, stream>>>(valueh, offbb, wallb, refp, attn);
    // 5. out-proj + residual + LN1 (emits f32 x and bf16 xb)
    gemm_ln_k<0><<<MT128, 256, 0, stream>>>(attn, woutT, b_out, g1, be1, src, sel, outx, xtail, xb, 256);
    // 6. FFN + LN2
    mfma_gemm128_k<1><<<dim3(MT128, 8), 256, 0, stream>>>(xb, wff1T, b_ff1, nullptr, hb, nullptr, NBQ, 256, 1024);
    gemm_ln_k<1><<<MT128, 256, 0, stream>>>(hb, wff2T, b_ff2, g2, be2, nullptr, nullptr, outx, xtail, nullptr, 1024);
    // 7. VT weight converts + token prep
    cvt_wT_k<<<dim3(24, 8, 4), 256, 0, stream>>>(vt_wqkv,  wqkvT,  256, 768);
    cvt_wT_k<<<dim3(8, 8, 4),  256, 0, stream>>>(vt_wproj, wprojT, 256, 256);
    cvt_wT_k<<<dim3(32, 8, 4), 256, 0, stream>>>(vt_wfc1,  wfc1T,  256, 1024);
    cvt_wT_k<<<dim3(8, 32, 4), 256, 0, stream>>>(vt_wfc2,  wfc2T,  1024, 256);
    vt_prep_k<<<NVROW / 4, 256, 0, stream>>>(xtail, seen, vtsf, vtsb);
    // 8. VT chain
    mfma_bgemm_k<0><<<dim3(2, 12, 8), 256, 0, stream>>>(vtsb, wqkvT, vt_bqkv, qkvf, nullptr, TVT, 256, 768);
    vt_attn_k<<<BB * NLV * NH, 128, 0, stream>>>(qkvf, obufb);
    mfma_bgemm_k<0><<<dim3(2, 4, 8),  256, 0, stream>>>(obufb, wprojT, vt_bproj, yy, nullptr, TVT, 256, 256);
    vt_ln_k<0><<<NVROW / 4, 256, 0, stream>>>(yy, vtsf, vt_g3, vt_b3, vts2f, vts2b, nullptr, nullptr);
    mfma_bgemm_k<3><<<dim3(2, 16, 8), 256, 0, stream>>>(vts2b, wfc1T, vt_bfc1, nullptr, hvtb, TVT, 256, 1024);
    mfma_bgemm_k<0><<<dim3(2, 4, 8),  256, 0, stream>>>(hvtb, wfc2T, vt_bfc2, yy, nullptr, TVT, 1024, 256);
    vt_ln_k<1><<<NVROW / 4, 256, 0, stream>>>(yy, vts2f, vt_g4, vt_b4, nullptr, nullptr, out_sel, out_seen);
}